// Round 3
// baseline (372.264 us; speedup 1.0000x reference)
//
#include <hip/hip_runtime.h>
#include <hip/hip_bf16.h>

#define D_MODEL 256
#define D_HID   128
#define SEQ     1024
#define NBATCH  32
#define NROWS   (NBATCH * SEQ)    // 32768
#define MASKV   -10000.0f
#define EPSLN   1e-5f

typedef unsigned short u16;
using bf16x8 = __attribute__((ext_vector_type(8))) short;
using f32x4  = __attribute__((ext_vector_type(4))) float;

union U8 { uint4 v; u16 s[8]; };

__device__ __forceinline__ float bf2f(u16 u) {
    unsigned int x = ((unsigned int)u) << 16;
    return __uint_as_float(x);
}
__device__ __forceinline__ u16 f2bf(float f) {
    unsigned int u = __float_as_uint(f);
    u += 0x7fff + ((u >> 16) & 1);   // RNE
    return (u16)(u >> 16);
}
__device__ __forceinline__ void load4(const float* p, float* f) {
    float4 a = *(const float4*)p;
    f[0] = a.x; f[1] = a.y; f[2] = a.z; f[3] = a.w;
}
__device__ __forceinline__ void load4(const u16* p, float* f) {
    ushort4 v = *(const ushort4*)p;
    f[0] = bf2f(v.x); f[1] = bf2f(v.y); f[2] = bf2f(v.z); f[3] = bf2f(v.w);
}
// async global->LDS, 16B per lane; LDS dest = wave-uniform base + lane*16
__device__ __forceinline__ void gload16(const u16* g, u16* l) {
    __builtin_amdgcn_global_load_lds(
        (const __attribute__((address_space(1))) void*)g,
        (__attribute__((address_space(3))) void*)l, 16, 0, 0);
}

// DPP cross-lane: VALU-pipe butterfly over the 16 'row' lanes.
template <int CTRL>
__device__ __forceinline__ float dpp_mov(float v) {
    return __int_as_float(__builtin_amdgcn_update_dpp(
        0, __float_as_int(v), CTRL, 0xf, 0xf, true));
}
__device__ __forceinline__ float red16_max(float v) {
    v = fmaxf(v, dpp_mov<0xB1>(v));
    v = fmaxf(v, dpp_mov<0x4E>(v));
    v = fmaxf(v, dpp_mov<0x141>(v));
    v = fmaxf(v, dpp_mov<0x140>(v));
    return v;
}
__device__ __forceinline__ float red16_sum(float v) {
    v += dpp_mov<0xB1>(v);
    v += dpp_mov<0x4E>(v);
    v += dpp_mov<0x141>(v);
    v += dpp_mov<0x140>(v);
    return v;
}

// ---------------------------------------------------------------------------
// Weight transposes: fp32 W[K][N] -> bf16 WT[N][K]
// ---------------------------------------------------------------------------
__global__ __launch_bounds__(256) void transpose_weights(
    const float* __restrict__ wqkv, u16* __restrict__ wqkvT,
    const float* __restrict__ wproj, u16* __restrict__ wprojT,
    const float* __restrict__ wfc1, u16* __restrict__ wfc1T,
    const float* __restrict__ wfc2, u16* __restrict__ wfc2T) {
    int tid = blockIdx.x * 256 + threadIdx.x;
    int stride = gridDim.x * 256;
    for (int i = tid; i < 768 * 256; i += stride) {
        int n = i >> 8, k = i & 255;
        wqkvT[i] = f2bf(wqkv[k * 768 + n]);
    }
    for (int i = tid; i < 256 * 256; i += stride) {
        int n = i >> 8, k = i & 255;
        wprojT[i] = f2bf(wproj[k * 256 + n]);
    }
    for (int i = tid; i < 128 * 256; i += stride) {
        int n = i >> 8, k = i & 255;
        wfc1T[i] = f2bf(wfc1[k * 128 + n]);
    }
    for (int i = tid; i < 256 * 128; i += stride) {
        int n = i >> 7, k = i & 127;
        wfc2T[i] = f2bf(wfc2[k * 256 + n]);
    }
}

// ---------------------------------------------------------------------------
// Fused LayerNorm: one wave per row (256 cols, 4/lane), writes bf16 row.
// ---------------------------------------------------------------------------
template <typename TX>
__global__ __launch_bounds__(256) void ln_fused(
    const TX* __restrict__ x, const float* __restrict__ gamma,
    const float* __restrict__ beta, u16* __restrict__ out) {
    int wave = threadIdx.x >> 6, lane = threadIdx.x & 63;
    int row = blockIdx.x * 4 + wave;
    float f[4];
    load4(x + (size_t)row * D_MODEL + lane * 4, f);
    float s  = f[0] + f[1] + f[2] + f[3];
    float sq = f[0] * f[0] + f[1] * f[1] + f[2] * f[2] + f[3] * f[3];
    #pragma unroll
    for (int off = 1; off < 64; off <<= 1) {
        s  += __shfl_xor(s, off);
        sq += __shfl_xor(sq, off);
    }
    float mu   = s * (1.0f / 256.0f);
    float var  = sq * (1.0f / 256.0f) - mu * mu;
    float rstd = rsqrtf(var + EPSLN);
    float g[4], be[4];
    load4(gamma + lane * 4, g);
    load4(beta + lane * 4, be);
    ushort4 o;
    o.x = f2bf((f[0] - mu) * rstd * g[0] + be[0]);
    o.y = f2bf((f[1] - mu) * rstd * g[1] + be[1]);
    o.z = f2bf((f[2] - mu) * rstd * g[2] + be[2]);
    o.w = f2bf((f[3] - mu) * rstd * g[3] + be[3]);
    *(ushort4*)(out + (size_t)row * D_MODEL + lane * 4) = o;
}

// ---------------------------------------------------------------------------
// 128x64 GEMM tile mainloop. 4 waves in 2x2; each wave 64x32 (acc[4][2]).
// ---------------------------------------------------------------------------
#define GEMM_LDS_ELEMS ((128 + 64) * 136)

template <int K>
__device__ __forceinline__ void gemm_tile(
    const u16* __restrict__ A, const u16* __restrict__ BT,
    int m0, int n0, u16* lds, f32x4 acc[4][2]) {
    constexpr int KC = 128, KP = 136;
    u16* ldsA = lds;
    u16* ldsB = lds + 128 * KP;
    const int tid = threadIdx.x;
    const int lane = tid & 63, wave = tid >> 6;
    const int wr = (wave >> 1) * 64, wc = (wave & 1) * 32;
    const int row = lane & 15, quad = lane >> 4;

    for (int ks = 0; ks < K; ks += KC) {
        __syncthreads();
        for (int i = tid; i < 2048; i += 256) {          // A: 128 x 128
            int i8 = i * 8;
            int r = i8 >> 7, c = i8 & 127;
            *(uint4*)(ldsA + r * KP + c) =
                *(const uint4*)(A + (size_t)(m0 + r) * K + ks + c);
        }
        for (int i = tid; i < 1024; i += 256) {          // B: 64 x 128
            int i8 = i * 8;
            int r = i8 >> 7, c = i8 & 127;
            *(uint4*)(ldsB + r * KP + c) =
                *(const uint4*)(BT + (size_t)(n0 + r) * K + ks + c);
        }
        __syncthreads();
        #pragma unroll
        for (int k0 = 0; k0 < KC; k0 += 32) {
            bf16x8 a[4], b[2];
            #pragma unroll
            for (int mi = 0; mi < 4; mi++)
                a[mi] = *(const bf16x8*)(ldsA + (wr + mi * 16 + row) * KP + k0 + quad * 8);
            #pragma unroll
            for (int nj = 0; nj < 2; nj++)
                b[nj] = *(const bf16x8*)(ldsB + (wc + nj * 16 + row) * KP + k0 + quad * 8);
            #pragma unroll
            for (int mi = 0; mi < 4; mi++)
                #pragma unroll
                for (int nj = 0; nj < 2; nj++)
                    acc[mi][nj] = __builtin_amdgcn_mfma_f32_16x16x32_bf16(
                        a[mi], b[nj], acc[mi][nj], 0, 0, 0);
        }
    }
}

#define ZERO_ACC(acc)                                        \
    _Pragma("unroll") for (int i_ = 0; i_ < 4; i_++)         \
    _Pragma("unroll") for (int j_ = 0; j_ < 2; j_++)         \
    _Pragma("unroll") for (int e_ = 0; e_ < 4; e_++) acc[i_][j_][e_] = 0.0f;

#define EPILOG_IDX                                           \
    int lane = threadIdx.x & 63, wave = threadIdx.x >> 6;    \
    int wr = (wave >> 1) * 64, wc = (wave & 1) * 32;         \
    int row = lane & 15, quad = lane >> 4;

// QKV: h @ wqkv + b -> q (pre-scaled 1/16), k, vT[b,256,s]
__global__ __launch_bounds__(256) void gemm_qkv(
    const u16* __restrict__ h, const u16* __restrict__ wqkvT,
    const float* __restrict__ b_qkv,
    u16* __restrict__ q, u16* __restrict__ kk, u16* __restrict__ vT) {
    __shared__ u16 lds[GEMM_LDS_ELEMS];
    f32x4 acc[4][2];
    ZERO_ACC(acc)
    int m0 = blockIdx.x * 128, n0 = blockIdx.y * 64;
    gemm_tile<256>(h, wqkvT, m0, n0, lds, acc);
    EPILOG_IDX
    #pragma unroll
    for (int mi = 0; mi < 4; mi++) {
        #pragma unroll
        for (int nj = 0; nj < 2; nj++) {
            int gn = n0 + wc + nj * 16 + row;
            float bias = b_qkv[gn];
            int gm = m0 + wr + mi * 16 + quad * 4;
            if (gn < 256) {          // q, pre-scaled by 1/sqrt(D)=1/16
                #pragma unroll
                for (int r = 0; r < 4; r++)
                    q[(size_t)(gm + r) * 256 + gn] =
                        f2bf((acc[mi][nj][r] + bias) * 0.0625f);
            } else if (gn < 512) {   // k
                int col = gn - 256;
                #pragma unroll
                for (int r = 0; r < 4; r++)
                    kk[(size_t)(gm + r) * 256 + col] = f2bf(acc[mi][nj][r] + bias);
            } else {                 // v -> vT[b][d][s]
                int d = gn - 512;
                int b = gm >> 10, s = gm & 1023;
                ushort4 pack;
                pack.x = f2bf(acc[mi][nj][0] + bias);
                pack.y = f2bf(acc[mi][nj][1] + bias);
                pack.z = f2bf(acc[mi][nj][2] + bias);
                pack.w = f2bf(acc[mi][nj][3] + bias);
                *(ushort4*)(vT + ((size_t)(b * 256 + d) << 10) + s) = pack;
            }
        }
    }
}

// proj: ao @ wproj + b + residual(x fp32) -> x2 (bf16)
__global__ __launch_bounds__(256) void gemm_proj(
    const u16* __restrict__ ao, const u16* __restrict__ wprojT,
    const float* __restrict__ b_proj, const float* __restrict__ x_in,
    u16* __restrict__ x2) {
    __shared__ u16 lds[GEMM_LDS_ELEMS];
    f32x4 acc[4][2];
    ZERO_ACC(acc)
    int m0 = blockIdx.x * 128, n0 = blockIdx.y * 64;
    gemm_tile<256>(ao, wprojT, m0, n0, lds, acc);
    EPILOG_IDX
    #pragma unroll
    for (int mi = 0; mi < 4; mi++)
        #pragma unroll
        for (int nj = 0; nj < 2; nj++) {
            int gn = n0 + wc + nj * 16 + row;
            float bias = b_proj[gn];
            int gm = m0 + wr + mi * 16 + quad * 4;
            #pragma unroll
            for (int r = 0; r < 4; r++) {
                size_t idx = (size_t)(gm + r) * 256 + gn;
                x2[idx] = f2bf(acc[mi][nj][r] + bias + x_in[idx]);
            }
        }
}

// fc1: h2 @ wfc1 + b, ReLU -> a1
__global__ __launch_bounds__(256) void gemm_fc1(
    const u16* __restrict__ h2, const u16* __restrict__ wfc1T,
    const float* __restrict__ b_fc1, u16* __restrict__ a1) {
    __shared__ u16 lds[GEMM_LDS_ELEMS];
    f32x4 acc[4][2];
    ZERO_ACC(acc)
    int m0 = blockIdx.x * 128, n0 = blockIdx.y * 64;
    gemm_tile<256>(h2, wfc1T, m0, n0, lds, acc);
    EPILOG_IDX
    #pragma unroll
    for (int mi = 0; mi < 4; mi++)
        #pragma unroll
        for (int nj = 0; nj < 2; nj++) {
            int gn = n0 + wc + nj * 16 + row;
            float bias = b_fc1[gn];
            int gm = m0 + wr + mi * 16 + quad * 4;
            #pragma unroll
            for (int r = 0; r < 4; r++) {
                float v = acc[mi][nj][r] + bias;
                a1[(size_t)(gm + r) * 128 + gn] = f2bf(fmaxf(v, 0.0f));
            }
        }
}

// fc2: a1 @ wfc2 + b + residual(x2) -> out (fp32)
__global__ __launch_bounds__(256) void gemm_fc2(
    const u16* __restrict__ a1, const u16* __restrict__ wfc2T,
    const float* __restrict__ b_fc2, const u16* __restrict__ x2,
    float* __restrict__ out) {
    __shared__ u16 lds[GEMM_LDS_ELEMS];
    f32x4 acc[4][2];
    ZERO_ACC(acc)
    int m0 = blockIdx.x * 128, n0 = blockIdx.y * 64;
    gemm_tile<128>(a1, wfc2T, m0, n0, lds, acc);
    EPILOG_IDX
    #pragma unroll
    for (int mi = 0; mi < 4; mi++)
        #pragma unroll
        for (int nj = 0; nj < 2; nj++) {
            int gn = n0 + wc + nj * 16 + row;
            float bias = b_fc2[gn];
            int gm = m0 + wr + mi * 16 + quad * 4;
            #pragma unroll
            for (int r = 0; r < 4; r++) {
                size_t idx = (size_t)(gm + r) * 256 + gn;
                out[idx] = acc[mi][nj][r] + bias + bf2f(x2[idx]);
            }
        }
}

// ---------------------------------------------------------------------------
// Flash attention v6: 128 q-rows/block, 4 waves x 32 rows (2 MFMA A-frags per
// wave). Each LDS K/V fragment read feeds TWO MFMAs -> LDS read traffic per
// FLOP halves vs v5 (the measured bottleneck: MfmaUtil 9% with LDS pipe
// saturated). Per batch 8 q-tiles (4qt+4 k-tiles each), cut into 16 chunks of
// <=12 k-tiles -> grid 512 = exact 2-blocks/CU residency, consecutive-pair
// durations balanced. qt0-2 chunks write final rows; qt3-7 chunks write
// unnormalized (m,l,O) partials (col-major, vectorized) merged by attn_merge.
// A wave's 32 rows span exactly one k-tile: wlast = 4qt + wave.
// ---------------------------------------------------------------------------
__constant__ unsigned char CQT[16] = {5,1,5,3,2,3,4,7,4,7,6,6,6,7,0,7};
__constant__ unsigned char CLO[16] = {0,0,12,0,0,8,0,0,10,8,0,10,19,16,0,24};
__constant__ unsigned char CHI[16] = {12,8,24,8,12,16,10,8,20,16,10,19,28,24,4,32};
__constant__ unsigned char CPI[16] = {4,255,5,0,255,1,2,9,3,10,6,7,8,11,255,12};

__global__ __launch_bounds__(256, 2) void attn_kernel(
    const u16* __restrict__ q, const u16* __restrict__ k,
    const u16* __restrict__ vT, u16* __restrict__ ao,
    u16* __restrict__ part, float* __restrict__ ml) {
    __shared__ u16 k_lds[2][32 * 256];   // 2 x 16 KB, K tile [s][d]
    __shared__ u16 v_lds[2][256 * 32];   // 2 x 16 KB, V^T tile [d][s]
    __shared__ u16 p_lds[4][32 * 40];    // 10 KB, wave-private P staging

    int j = blockIdx.x;
    int b = j >> 4, c = j & 15;
    int qt = CQT[c], lo = CLO[c], hi = CHI[c], pi = CPI[c];

    int tid = threadIdx.x;
    int lane = tid & 63, wave = tid >> 6;
    int row = lane & 15, quad = lane >> 4;
    int qrowbase = qt * 128 + wave * 32;

    const u16* qb = q + ((size_t)b << 10) * 256;
    const u16* kb = k + ((size_t)b << 10) * 256;
    const u16* vb = vT + (((size_t)b * 256) << 10);

    const int kxor = (row & 7) << 3;   // u16-unit XOR for K reads
    const int vxor = (row & 6) << 2;   // u16-unit XOR for V reads

    // Q fragments: 2 x 16 rows, in registers for the whole kernel
    bf16x8 qf[2][8];
    #pragma unroll
    for (int mi = 0; mi < 2; mi++)
        #pragma unroll
        for (int kf = 0; kf < 8; kf++)
            qf[mi][kf] = *(const bf16x8*)(qb +
                (size_t)(qrowbase + mi * 16 + row) * 256 + kf * 32 + quad * 8);

    f32x4 o[2][16];
    #pragma unroll
    for (int mi = 0; mi < 2; mi++)
        #pragma unroll
        for (int n = 0; n < 16; n++)
            #pragma unroll
            for (int e = 0; e < 4; e++) o[mi][n][e] = 0.0f;
    float m_i[2][4], l_i[2][4];
    #pragma unroll
    for (int mi = 0; mi < 2; mi++)
        #pragma unroll
        for (int r = 0; r < 4; r++) { m_i[mi][r] = -1e30f; l_i[mi][r] = 0.0f; }

    int wlast = 4 * qt + wave;           // this wave's diagonal k-tile

    auto stage = [&](int bf, int kt) {
        int k0 = kt << 5;
        #pragma unroll
        for (int cc = 0; cc < 4; cc++) {
            int blk = wave * 4 + cc;
            int B = (blk << 10) + lane * 16;          // byte offset in 16KB tile
            // K: 32 rows x 512 B
            int rk = B >> 9;
            int ck = (B & 511) ^ ((rk & 7) << 4);
            gload16(kb + (size_t)(k0 + rk) * 256 + (ck >> 1),
                    &k_lds[bf][blk << 9]);
            // V^T: 256 rows x 64 B
            int rv = B >> 6;
            int cv = (B & 63) ^ ((rv & 6) << 3);
            gload16(vb + ((size_t)rv << 10) + k0 + (cv >> 1),
                    &v_lds[bf][blk << 9]);
        }
    };

    stage(0, lo);
    __syncthreads();                       // vmcnt(0) drain + barrier

    for (int kt = lo; kt < hi; kt++) {
        int cur = (kt - lo) & 1;
        if (kt + 1 < hi) stage(cur ^ 1, kt + 1);   // prefetch next tile
        if (kt <= wlast) {
            const u16* kl = k_lds[cur];
            const u16* vl = v_lds[cur];

            // S = Q K^T : 32 x 32 (2 m-frags x 2 n-frags); K frag read once,
            // used by both m-frags.
            f32x4 sf[2][2];
            #pragma unroll
            for (int mi = 0; mi < 2; mi++)
                #pragma unroll
                for (int jn = 0; jn < 2; jn++)
                    #pragma unroll
                    for (int e = 0; e < 4; e++) sf[mi][jn][e] = 0.0f;
            __builtin_amdgcn_s_setprio(1);
            #pragma unroll
            for (int kf = 0; kf < 8; kf++)
                #pragma unroll
                for (int jn = 0; jn < 2; jn++) {
                    bf16x8 bfrag = *(const bf16x8*)(kl +
                        ((((jn * 16 + row) * 256) + kf * 32 + quad * 8) ^ kxor));
                    #pragma unroll
                    for (int mi = 0; mi < 2; mi++)
                        sf[mi][jn] = __builtin_amdgcn_mfma_f32_16x16x32_bf16(
                            qf[mi][kf], bfrag, sf[mi][jn], 0, 0, 0);
                }
            __builtin_amdgcn_s_setprio(0);

            int kk0 = kt * 32;
            bool diag = (kt == wlast);     // only the diagonal tile masks
            if (diag) {
                #pragma unroll
                for (int mi = 0; mi < 2; mi++)
                    #pragma unroll
                    for (int jn = 0; jn < 2; jn++)
                        #pragma unroll
                        for (int r = 0; r < 4; r++)
                            if (kk0 + jn * 16 + row >
                                qrowbase + mi * 16 + quad * 4 + r)
                                sf[mi][jn][r] = MASKV;
            }

            // online softmax with defer-max (THR=8); DPP reduces (VALU pipe)
            float pmax[2][4];
            int need = 0;
            #pragma unroll
            for (int mi = 0; mi < 2; mi++)
                #pragma unroll
                for (int r = 0; r < 4; r++) {
                    pmax[mi][r] = red16_max(fmaxf(sf[mi][0][r], sf[mi][1][r]));
                    need |= (pmax[mi][r] > m_i[mi][r] + 8.0f) ? 1 : 0;
                }
            if (__any(need)) {
                #pragma unroll
                for (int mi = 0; mi < 2; mi++)
                    #pragma unroll
                    for (int r = 0; r < 4; r++) {
                        float mnew = fmaxf(m_i[mi][r], pmax[mi][r]);
                        float al = __expf(m_i[mi][r] - mnew);
                        m_i[mi][r] = mnew;
                        l_i[mi][r] *= al;
                        #pragma unroll
                        for (int n = 0; n < 16; n++) o[mi][n][r] *= al;
                    }
            }
            #pragma unroll
            for (int mi = 0; mi < 2; mi++)
                #pragma unroll
                for (int r = 0; r < 4; r++) {
                    float ps = 0.0f;
                    #pragma unroll
                    for (int jn = 0; jn < 2; jn++) {
                        sf[mi][jn][r] = __expf(sf[mi][jn][r] - m_i[mi][r]);
                        ps += sf[mi][jn][r];
                    }
                    l_i[mi][r] += red16_sum(ps);
                }

            // P: C-layout -> wave-private LDS -> A-layout (2 frags, K=32)
            u16* pw = p_lds[wave];
            #pragma unroll
            for (int mi = 0; mi < 2; mi++)
                #pragma unroll
                for (int jn = 0; jn < 2; jn++)
                    #pragma unroll
                    for (int r = 0; r < 4; r++)
                        pw[(mi * 16 + quad * 4 + r) * 40 + jn * 16 + row] =
                            f2bf(sf[mi][jn][r]);
            bf16x8 pf0 = *(const bf16x8*)(pw + row * 40 + quad * 8);
            bf16x8 pf1 = *(const bf16x8*)(pw + (16 + row) * 40 + quad * 8);

            // O += P V  (V frag read once, used by both m-frags)
            __builtin_amdgcn_s_setprio(1);
            #pragma unroll
            for (int n = 0; n < 16; n++) {
                bf16x8 bv = *(const bf16x8*)(vl +
                    ((((n * 16 + row) * 32) + quad * 8) ^ vxor));
                o[0][n] = __builtin_amdgcn_mfma_f32_16x16x32_bf16(pf0, bv, o[0][n], 0, 0, 0);
                o[1][n] = __builtin_amdgcn_mfma_f32_16x16x32_bf16(pf1, bv, o[1][n], 0, 0, 0);
            }
            __builtin_amdgcn_s_setprio(0);
        }
        __syncthreads();   // vmcnt(0): prefetched tile landed; buffers swap
    }

    if (pi == 255) {
        // full-range chunk: normalize and store final bf16
        u16* aob = ao + (((size_t)b << 10) + qrowbase) * 256;
        #pragma unroll
        for (int mi = 0; mi < 2; mi++)
            #pragma unroll
            for (int r = 0; r < 4; r++) {
                float inv = 1.0f / l_i[mi][r];
                #pragma unroll
                for (int n = 0; n < 16; n++)
                    aob[(size_t)(mi * 16 + quad * 4 + r) * 256 + n * 16 + row] =
                        f2bf(o[mi][n][r] * inv);
            }
    } else {
        // split chunk: write unnormalized O col-major [col][128 rows] + (m,l)
        u16* pb = part + ((size_t)(b * 13 + pi) << 15);
        int rbase = wave * 32 + quad * 4;
        #pragma unroll
        for (int mi = 0; mi < 2; mi++)
            #pragma unroll
            for (int n = 0; n < 16; n++) {
                ushort4 pk;
                pk.x = f2bf(o[mi][n][0]);
                pk.y = f2bf(o[mi][n][1]);
                pk.z = f2bf(o[mi][n][2]);
                pk.w = f2bf(o[mi][n][3]);
                *(ushort4*)(pb + (size_t)(n * 16 + row) * 128 + rbase + mi * 16) = pk;
            }
        if (row == 0) {
            #pragma unroll
            for (int mi = 0; mi < 2; mi++)
                #pragma unroll
                for (int r = 0; r < 4; r++) {
                    int rt = wave * 32 + mi * 16 + quad * 4 + r;
                    float2 v2; v2.x = m_i[mi][r]; v2.y = l_i[mi][r];
                    *(float2*)(ml + ((size_t)((b * 13 + pi) * 128 + rt)) * 2) = v2;
                }
        }
    }
}

// Merge 2-4 k-range chunk partials per split q-tile (qt 3..7).
// Partials are col-major [256 cols][128 rows]; thread = col, rows contiguous.
__constant__ unsigned char SP_PB[5] = {0, 2, 4, 6, 9};
__constant__ unsigned char SP_NC[5] = {2, 2, 2, 3, 4};

__global__ __launch_bounds__(256) void attn_merge(
    const u16* __restrict__ part, const float* __restrict__ ml,
    u16* __restrict__ ao) {
    __shared__ float s_sc[4][128];
    int j = blockIdx.x;                  // 0..159 = b*5 + t
    int b = j / 5, t = j - b * 5;
    int pb0 = SP_PB[t], nc = SP_NC[t];
    int tid = threadIdx.x;
    if (tid < 128) {
        int r = tid;
        float mm[4], lv[4];
        float mx = -1e30f;
        for (int cc = 0; cc < nc; cc++) {
            const float* p2 = ml + ((size_t)((b * 13 + pb0 + cc) * 128 + r)) * 2;
            mm[cc] = p2[0]; lv[cc] = p2[1];
            mx = fmaxf(mx, mm[cc]);
        }
        float lsum = 0.0f;
        for (int cc = 0; cc < nc; cc++) {
            mm[cc] = __expf(mm[cc] - mx);
            lsum += lv[cc] * mm[cc];
        }
        float inv = 1.0f / lsum;
        for (int cc = 0; cc < nc; cc++) s_sc[cc][r] = mm[cc] * inv;
    }
    __syncthreads();
    int col = tid;
    const u16* pc[4];
    for (int cc = 0; cc < 4; cc++)
        pc[cc] = part + ((size_t)(b * 13 + pb0 + (cc < nc ? cc : 0)) << 15)
               + (size_t)col * 128;
    u16* dst = ao + ((size_t)((b << 10) + (t + 3) * 128)) * 256 + col;
    for (int u = 0; u < 16; u++) {       // 8 rows per group
        float acc[8];
        #pragma unroll
        for (int e = 0; e < 8; e++) acc[e] = 0.0f;
        for (int cc = 0; cc < nc; cc++) {
            U8 v; v.v = *(const uint4*)(pc[cc] + u * 8);
            #pragma unroll
            for (int e = 0; e < 8; e++)
                acc[e] += s_sc[cc][u * 8 + e] * bf2f(v.s[e]);
        }
        #pragma unroll
        for (int e = 0; e < 8; e++)
            dst[(size_t)(u * 8 + e) * 256] = f2bf(acc[e]);
    }
}

// ---------------------------------------------------------------------------
extern "C" void kernel_launch(void* const* d_in, const int* in_sizes, int n_in,
                              void* d_out, int out_size, void* d_ws, size_t ws_size,
                              hipStream_t stream) {
    const float* x      = (const float*)d_in[0];
    const float* ln1_s  = (const float*)d_in[1];
    const float* ln1_b  = (const float*)d_in[2];
    const float* w_qkv  = (const float*)d_in[3];
    const float* b_qkv  = (const float*)d_in[4];
    const float* w_proj = (const float*)d_in[5];
    const float* b_proj = (const float*)d_in[6];
    const float* ln2_s  = (const float*)d_in[7];
    const float* ln2_b  = (const float*)d_in[8];
    const float* w_fc1  = (const float*)d_in[9];
    const float* b_fc1  = (const float*)d_in[10];
    const float* w_fc2  = (const float*)d_in[11];
    const float* b_fc2  = (const float*)d_in[12];
    float* out = (float*)d_out;

    // d_out reuse timeline:
    //   ln1 -> h (first 16.8MB) -> consumed by gemm_qkv
    //   attn partials: 27.3MB col-major bf16 from d_out base + (m,l) 426KB at
    //   float offset 7.2M (28.8MB) -> consumed by attn_merge
    //   ln2 -> h2 (second 16.8MB, overwrites dead partial tail)
    //   fc2 -> overwrites all of d_out last.
    u16* h  = (u16*)d_out;                     // LN1(x)
    u16* h2 = h + (size_t)NROWS * 256;         // LN2(x2)

    u16* W = (u16*)d_ws;
    u16* wqkvT  = W;                           // 768*256
    u16* wprojT = wqkvT + 196608;              // 256*256
    u16* wfc1T  = wprojT + 65536;              // 128*256
    u16* wfc2T  = wfc1T + 32768;               // 256*128
    u16* buf1   = wfc2T + 32768;               // q, then attn-out (in place)
    u16* buf2   = buf1 + (size_t)NROWS * 256;  // k, then x2
    u16* buf3   = buf2 + (size_t)NROWS * 256;  // vT, then a1

    u16*   part  = (u16*)d_out;                // attn partial O (bf16, col-major)
    float* mlbuf = (float*)d_out + 7200000;    // attn partial (m,l)

    transpose_weights<<<dim3(64), dim3(256), 0, stream>>>(
        w_qkv, wqkvT, w_proj, wprojT, w_fc1, wfc1T, w_fc2, wfc2T);
    ln_fused<float><<<dim3(NROWS / 4), dim3(256), 0, stream>>>(
        x, ln1_s, ln1_b, h);
    gemm_qkv<<<dim3(NROWS / 128, 12), dim3(256), 0, stream>>>(
        h, wqkvT, b_qkv, buf1, buf2, buf3);
    attn_kernel<<<dim3(512), dim3(256), 0, stream>>>(
        buf1, buf2, buf3, buf1, part, mlbuf);
    attn_merge<<<dim3(160), dim3(256), 0, stream>>>(
        part, mlbuf, buf1);
    gemm_proj<<<dim3(NROWS / 128, 4), dim3(256), 0, stream>>>(
        buf1, wprojT, b_proj, x, buf2);
    ln_fused<u16><<<dim3(NROWS / 4), dim3(256), 0, stream>>>(
        buf2, ln2_s, ln2_b, h2);
    gemm_fc1<<<dim3(NROWS / 128, 2), dim3(256), 0, stream>>>(
        h2, wfc1T, b_fc1, buf3);
    gemm_fc2<<<dim3(NROWS / 128, 4), dim3(256), 0, stream>>>(
        buf3, wfc2T, b_fc2, buf2, out);
}

// Round 4
// 341.773 us; speedup vs baseline: 1.0892x; 1.0892x over previous
//
#include <hip/hip_runtime.h>
#include <hip/hip_bf16.h>

#define D_MODEL 256
#define D_HID   128
#define SEQ     1024
#define NBATCH  32
#define NROWS   (NBATCH * SEQ)    // 32768
#define MASKV   -10000.0f
#define EPSLN   1e-5f

typedef unsigned short u16;
using bf16x8 = __attribute__((ext_vector_type(8))) short;
using f32x4  = __attribute__((ext_vector_type(4))) float;

union U8 { uint4 v; u16 s[8]; };

__device__ __forceinline__ float bf2f(u16 u) {
    unsigned int x = ((unsigned int)u) << 16;
    return __uint_as_float(x);
}
__device__ __forceinline__ u16 f2bf(float f) {
    unsigned int u = __float_as_uint(f);
    u += 0x7fff + ((u >> 16) & 1);   // RNE
    return (u16)(u >> 16);
}
__device__ __forceinline__ void load4(const float* p, float* f) {
    float4 a = *(const float4*)p;
    f[0] = a.x; f[1] = a.y; f[2] = a.z; f[3] = a.w;
}
__device__ __forceinline__ void load4(const u16* p, float* f) {
    ushort4 v = *(const ushort4*)p;
    f[0] = bf2f(v.x); f[1] = bf2f(v.y); f[2] = bf2f(v.z); f[3] = bf2f(v.w);
}
// async global->LDS, 16B per lane; LDS dest = wave-uniform base + lane*16
__device__ __forceinline__ void gload16(const u16* g, u16* l) {
    __builtin_amdgcn_global_load_lds(
        (const __attribute__((address_space(1))) void*)g,
        (__attribute__((address_space(3))) void*)l, 16, 0, 0);
}

// DPP cross-lane: VALU-pipe butterfly over the 16 'row' lanes.
template <int CTRL>
__device__ __forceinline__ float dpp_mov(float v) {
    return __int_as_float(__builtin_amdgcn_update_dpp(
        0, __float_as_int(v), CTRL, 0xf, 0xf, true));
}
__device__ __forceinline__ float red16_max(float v) {
    v = fmaxf(v, dpp_mov<0xB1>(v));
    v = fmaxf(v, dpp_mov<0x4E>(v));
    v = fmaxf(v, dpp_mov<0x141>(v));
    v = fmaxf(v, dpp_mov<0x140>(v));
    return v;
}
__device__ __forceinline__ float red16_sum(float v) {
    v += dpp_mov<0xB1>(v);
    v += dpp_mov<0x4E>(v);
    v += dpp_mov<0x141>(v);
    v += dpp_mov<0x140>(v);
    return v;
}

// ---------------------------------------------------------------------------
// Weight transposes: fp32 W[K][N] -> bf16 WT[N][K]
// ---------------------------------------------------------------------------
__global__ __launch_bounds__(256) void transpose_weights(
    const float* __restrict__ wqkv, u16* __restrict__ wqkvT,
    const float* __restrict__ wproj, u16* __restrict__ wprojT,
    const float* __restrict__ wfc1, u16* __restrict__ wfc1T,
    const float* __restrict__ wfc2, u16* __restrict__ wfc2T) {
    int tid = blockIdx.x * 256 + threadIdx.x;
    int stride = gridDim.x * 256;
    for (int i = tid; i < 768 * 256; i += stride) {
        int n = i >> 8, k = i & 255;
        wqkvT[i] = f2bf(wqkv[k * 768 + n]);
    }
    for (int i = tid; i < 256 * 256; i += stride) {
        int n = i >> 8, k = i & 255;
        wprojT[i] = f2bf(wproj[k * 256 + n]);
    }
    for (int i = tid; i < 128 * 256; i += stride) {
        int n = i >> 8, k = i & 255;
        wfc1T[i] = f2bf(wfc1[k * 128 + n]);
    }
    for (int i = tid; i < 256 * 128; i += stride) {
        int n = i >> 7, k = i & 127;
        wfc2T[i] = f2bf(wfc2[k * 256 + n]);
    }
}

// ---------------------------------------------------------------------------
// Fused LayerNorm: one wave per row (256 cols, 4/lane), writes bf16 row.
// ---------------------------------------------------------------------------
template <typename TX>
__global__ __launch_bounds__(256) void ln_fused(
    const TX* __restrict__ x, const float* __restrict__ gamma,
    const float* __restrict__ beta, u16* __restrict__ out) {
    int wave = threadIdx.x >> 6, lane = threadIdx.x & 63;
    int row = blockIdx.x * 4 + wave;
    float f[4];
    load4(x + (size_t)row * D_MODEL + lane * 4, f);
    float s  = f[0] + f[1] + f[2] + f[3];
    float sq = f[0] * f[0] + f[1] * f[1] + f[2] * f[2] + f[3] * f[3];
    #pragma unroll
    for (int off = 1; off < 64; off <<= 1) {
        s  += __shfl_xor(s, off);
        sq += __shfl_xor(sq, off);
    }
    float mu   = s * (1.0f / 256.0f);
    float var  = sq * (1.0f / 256.0f) - mu * mu;
    float rstd = rsqrtf(var + EPSLN);
    float g[4], be[4];
    load4(gamma + lane * 4, g);
    load4(beta + lane * 4, be);
    ushort4 o;
    o.x = f2bf((f[0] - mu) * rstd * g[0] + be[0]);
    o.y = f2bf((f[1] - mu) * rstd * g[1] + be[1]);
    o.z = f2bf((f[2] - mu) * rstd * g[2] + be[2]);
    o.w = f2bf((f[3] - mu) * rstd * g[3] + be[3]);
    *(ushort4*)(out + (size_t)row * D_MODEL + lane * 4) = o;
}

// ---------------------------------------------------------------------------
// 128x64 GEMM tile mainloop. 4 waves in 2x2; each wave 64x32 (acc[4][2]).
// ---------------------------------------------------------------------------
#define GEMM_LDS_ELEMS ((128 + 64) * 136)

template <int K>
__device__ __forceinline__ void gemm_tile(
    const u16* __restrict__ A, const u16* __restrict__ BT,
    int m0, int n0, u16* lds, f32x4 acc[4][2]) {
    constexpr int KC = 128, KP = 136;
    u16* ldsA = lds;
    u16* ldsB = lds + 128 * KP;
    const int tid = threadIdx.x;
    const int lane = tid & 63, wave = tid >> 6;
    const int wr = (wave >> 1) * 64, wc = (wave & 1) * 32;
    const int row = lane & 15, quad = lane >> 4;

    for (int ks = 0; ks < K; ks += KC) {
        __syncthreads();
        for (int i = tid; i < 2048; i += 256) {          // A: 128 x 128
            int i8 = i * 8;
            int r = i8 >> 7, c = i8 & 127;
            *(uint4*)(ldsA + r * KP + c) =
                *(const uint4*)(A + (size_t)(m0 + r) * K + ks + c);
        }
        for (int i = tid; i < 1024; i += 256) {          // B: 64 x 128
            int i8 = i * 8;
            int r = i8 >> 7, c = i8 & 127;
            *(uint4*)(ldsB + r * KP + c) =
                *(const uint4*)(BT + (size_t)(n0 + r) * K + ks + c);
        }
        __syncthreads();
        #pragma unroll
        for (int k0 = 0; k0 < KC; k0 += 32) {
            bf16x8 a[4], b[2];
            #pragma unroll
            for (int mi = 0; mi < 4; mi++)
                a[mi] = *(const bf16x8*)(ldsA + (wr + mi * 16 + row) * KP + k0 + quad * 8);
            #pragma unroll
            for (int nj = 0; nj < 2; nj++)
                b[nj] = *(const bf16x8*)(ldsB + (wc + nj * 16 + row) * KP + k0 + quad * 8);
            #pragma unroll
            for (int mi = 0; mi < 4; mi++)
                #pragma unroll
                for (int nj = 0; nj < 2; nj++)
                    acc[mi][nj] = __builtin_amdgcn_mfma_f32_16x16x32_bf16(
                        a[mi], b[nj], acc[mi][nj], 0, 0, 0);
        }
    }
}

#define ZERO_ACC(acc)                                        \
    _Pragma("unroll") for (int i_ = 0; i_ < 4; i_++)         \
    _Pragma("unroll") for (int j_ = 0; j_ < 2; j_++)         \
    _Pragma("unroll") for (int e_ = 0; e_ < 4; e_++) acc[i_][j_][e_] = 0.0f;

#define EPILOG_IDX                                           \
    int lane = threadIdx.x & 63, wave = threadIdx.x >> 6;    \
    int wr = (wave >> 1) * 64, wc = (wave & 1) * 32;         \
    int row = lane & 15, quad = lane >> 4;

// QKV: h @ wqkv + b -> q (pre-scaled 1/16), k, vT[b,256,s]
__global__ __launch_bounds__(256) void gemm_qkv(
    const u16* __restrict__ h, const u16* __restrict__ wqkvT,
    const float* __restrict__ b_qkv,
    u16* __restrict__ q, u16* __restrict__ kk, u16* __restrict__ vT) {
    __shared__ u16 lds[GEMM_LDS_ELEMS];
    f32x4 acc[4][2];
    ZERO_ACC(acc)
    int m0 = blockIdx.x * 128, n0 = blockIdx.y * 64;
    gemm_tile<256>(h, wqkvT, m0, n0, lds, acc);
    EPILOG_IDX
    #pragma unroll
    for (int mi = 0; mi < 4; mi++) {
        #pragma unroll
        for (int nj = 0; nj < 2; nj++) {
            int gn = n0 + wc + nj * 16 + row;
            float bias = b_qkv[gn];
            int gm = m0 + wr + mi * 16 + quad * 4;
            if (gn < 256) {          // q, pre-scaled by 1/sqrt(D)=1/16
                #pragma unroll
                for (int r = 0; r < 4; r++)
                    q[(size_t)(gm + r) * 256 + gn] =
                        f2bf((acc[mi][nj][r] + bias) * 0.0625f);
            } else if (gn < 512) {   // k
                int col = gn - 256;
                #pragma unroll
                for (int r = 0; r < 4; r++)
                    kk[(size_t)(gm + r) * 256 + col] = f2bf(acc[mi][nj][r] + bias);
            } else {                 // v -> vT[b][d][s]
                int d = gn - 512;
                int b = gm >> 10, s = gm & 1023;
                ushort4 pack;
                pack.x = f2bf(acc[mi][nj][0] + bias);
                pack.y = f2bf(acc[mi][nj][1] + bias);
                pack.z = f2bf(acc[mi][nj][2] + bias);
                pack.w = f2bf(acc[mi][nj][3] + bias);
                *(ushort4*)(vT + ((size_t)(b * 256 + d) << 10) + s) = pack;
            }
        }
    }
}

// proj: ao @ wproj + b + residual(x fp32) -> x2 (bf16)
__global__ __launch_bounds__(256) void gemm_proj(
    const u16* __restrict__ ao, const u16* __restrict__ wprojT,
    const float* __restrict__ b_proj, const float* __restrict__ x_in,
    u16* __restrict__ x2) {
    __shared__ u16 lds[GEMM_LDS_ELEMS];
    f32x4 acc[4][2];
    ZERO_ACC(acc)
    int m0 = blockIdx.x * 128, n0 = blockIdx.y * 64;
    gemm_tile<256>(ao, wprojT, m0, n0, lds, acc);
    EPILOG_IDX
    #pragma unroll
    for (int mi = 0; mi < 4; mi++)
        #pragma unroll
        for (int nj = 0; nj < 2; nj++) {
            int gn = n0 + wc + nj * 16 + row;
            float bias = b_proj[gn];
            int gm = m0 + wr + mi * 16 + quad * 4;
            #pragma unroll
            for (int r = 0; r < 4; r++) {
                size_t idx = (size_t)(gm + r) * 256 + gn;
                x2[idx] = f2bf(acc[mi][nj][r] + bias + x_in[idx]);
            }
        }
}

// fc1: h2 @ wfc1 + b, ReLU -> a1
__global__ __launch_bounds__(256) void gemm_fc1(
    const u16* __restrict__ h2, const u16* __restrict__ wfc1T,
    const float* __restrict__ b_fc1, u16* __restrict__ a1) {
    __shared__ u16 lds[GEMM_LDS_ELEMS];
    f32x4 acc[4][2];
    ZERO_ACC(acc)
    int m0 = blockIdx.x * 128, n0 = blockIdx.y * 64;
    gemm_tile<256>(h2, wfc1T, m0, n0, lds, acc);
    EPILOG_IDX
    #pragma unroll
    for (int mi = 0; mi < 4; mi++)
        #pragma unroll
        for (int nj = 0; nj < 2; nj++) {
            int gn = n0 + wc + nj * 16 + row;
            float bias = b_fc1[gn];
            int gm = m0 + wr + mi * 16 + quad * 4;
            #pragma unroll
            for (int r = 0; r < 4; r++) {
                float v = acc[mi][nj][r] + bias;
                a1[(size_t)(gm + r) * 128 + gn] = f2bf(fmaxf(v, 0.0f));
            }
        }
}

// fc2: a1 @ wfc2 + b + residual(x2) -> out (fp32)
__global__ __launch_bounds__(256) void gemm_fc2(
    const u16* __restrict__ a1, const u16* __restrict__ wfc2T,
    const float* __restrict__ b_fc2, const u16* __restrict__ x2,
    float* __restrict__ out) {
    __shared__ u16 lds[GEMM_LDS_ELEMS];
    f32x4 acc[4][2];
    ZERO_ACC(acc)
    int m0 = blockIdx.x * 128, n0 = blockIdx.y * 64;
    gemm_tile<128>(a1, wfc2T, m0, n0, lds, acc);
    EPILOG_IDX
    #pragma unroll
    for (int mi = 0; mi < 4; mi++)
        #pragma unroll
        for (int nj = 0; nj < 2; nj++) {
            int gn = n0 + wc + nj * 16 + row;
            float bias = b_fc2[gn];
            int gm = m0 + wr + mi * 16 + quad * 4;
            #pragma unroll
            for (int r = 0; r < 4; r++) {
                size_t idx = (size_t)(gm + r) * 256 + gn;
                out[idx] = acc[mi][nj][r] + bias + bf2f(x2[idx]);
            }
        }
}

// ---------------------------------------------------------------------------
// Flash attention v7: v6's compute structure (128 q-rows/block, 4 waves x 32
// rows, 2 A-frags/wave so each LDS K/V fragment feeds 2 MFMAs) with the v5
// XCD-LOCAL INDEX MAPPING restored: block j -> b = j&31, chunk = j>>5.
// With round-robin blockIdx->XCD, all 16 chunks of batch b land on XCD b%8,
// so each XCD's 4-MB L2 holds exactly its 4 batches' K/V (4 x 1 MB) -> K/V
// staging hits L2. (v6 mapped b=j>>4: every XCD read all 32 batches = 32 MB
// -> L2 thrash, FETCH_SIZE 187 MB, 2x slowdown.)
// Chunk table ordered so the two chunks co-resident on one CU (c and c+8,
// same batch) have balanced durations (pair sums 16-20, mean 18).
// qt0-2 whole chunks write final rows; qt3-7 k-range chunks write
// unnormalized (m,l,O) partials (col-major) merged by attn_merge.
// ---------------------------------------------------------------------------
__constant__ unsigned char CQT[16] = {5,5,2,4,4,6,6,3, 7,7,0,7,7,1,6,3};
__constant__ unsigned char CLO[16] = {0,12,0,0,10,0,10,0, 0,8,0,16,24,0,19,8};
__constant__ unsigned char CHI[16] = {12,24,12,10,20,10,19,8, 8,16,4,24,32,8,28,16};
__constant__ unsigned char CPI[16] = {4,5,255,2,3,6,7,0, 9,10,255,11,12,255,8,1};

__global__ __launch_bounds__(256, 2) void attn_kernel(
    const u16* __restrict__ q, const u16* __restrict__ k,
    const u16* __restrict__ vT, u16* __restrict__ ao,
    u16* __restrict__ part, float* __restrict__ ml) {
    __shared__ u16 k_lds[2][32 * 256];   // 2 x 16 KB, K tile [s][d]
    __shared__ u16 v_lds[2][256 * 32];   // 2 x 16 KB, V^T tile [d][s]
    __shared__ u16 p_lds[4][32 * 40];    // 10 KB, wave-private P staging

    int j = blockIdx.x;
    int b = j & 31, c = j >> 5;          // batch fast-varying: XCD = b % 8
    int qt = CQT[c], lo = CLO[c], hi = CHI[c], pi = CPI[c];

    int tid = threadIdx.x;
    int lane = tid & 63, wave = tid >> 6;
    int row = lane & 15, quad = lane >> 4;
    int qrowbase = qt * 128 + wave * 32;

    const u16* qb = q + ((size_t)b << 10) * 256;
    const u16* kb = k + ((size_t)b << 10) * 256;
    const u16* vb = vT + (((size_t)b * 256) << 10);

    const int kxor = (row & 7) << 3;   // u16-unit XOR for K reads
    const int vxor = (row & 6) << 2;   // u16-unit XOR for V reads

    // Q fragments: 2 x 16 rows, in registers for the whole kernel
    bf16x8 qf[2][8];
    #pragma unroll
    for (int mi = 0; mi < 2; mi++)
        #pragma unroll
        for (int kf = 0; kf < 8; kf++)
            qf[mi][kf] = *(const bf16x8*)(qb +
                (size_t)(qrowbase + mi * 16 + row) * 256 + kf * 32 + quad * 8);

    f32x4 o[2][16];
    #pragma unroll
    for (int mi = 0; mi < 2; mi++)
        #pragma unroll
        for (int n = 0; n < 16; n++)
            #pragma unroll
            for (int e = 0; e < 4; e++) o[mi][n][e] = 0.0f;
    float m_i[2][4], l_i[2][4];
    #pragma unroll
    for (int mi = 0; mi < 2; mi++)
        #pragma unroll
        for (int r = 0; r < 4; r++) { m_i[mi][r] = -1e30f; l_i[mi][r] = 0.0f; }

    int wlast = 4 * qt + wave;           // this wave's diagonal k-tile

    auto stage = [&](int bf, int kt) {
        int k0 = kt << 5;
        #pragma unroll
        for (int cc = 0; cc < 4; cc++) {
            int blk = wave * 4 + cc;
            int B = (blk << 10) + lane * 16;          // byte offset in 16KB tile
            // K: 32 rows x 512 B
            int rk = B >> 9;
            int ck = (B & 511) ^ ((rk & 7) << 4);
            gload16(kb + (size_t)(k0 + rk) * 256 + (ck >> 1),
                    &k_lds[bf][blk << 9]);
            // V^T: 256 rows x 64 B
            int rv = B >> 6;
            int cv = (B & 63) ^ ((rv & 6) << 3);
            gload16(vb + ((size_t)rv << 10) + k0 + (cv >> 1),
                    &v_lds[bf][blk << 9]);
        }
    };

    stage(0, lo);
    __syncthreads();                       // vmcnt(0) drain + barrier

    for (int kt = lo; kt < hi; kt++) {
        int cur = (kt - lo) & 1;
        if (kt + 1 < hi) stage(cur ^ 1, kt + 1);   // prefetch next tile
        if (kt <= wlast) {
            const u16* kl = k_lds[cur];
            const u16* vl = v_lds[cur];

            // S = Q K^T : 32 x 32 (2 m-frags x 2 n-frags); K frag read once,
            // used by both m-frags.
            f32x4 sf[2][2];
            #pragma unroll
            for (int mi = 0; mi < 2; mi++)
                #pragma unroll
                for (int jn = 0; jn < 2; jn++)
                    #pragma unroll
                    for (int e = 0; e < 4; e++) sf[mi][jn][e] = 0.0f;
            __builtin_amdgcn_s_setprio(1);
            #pragma unroll
            for (int kf = 0; kf < 8; kf++)
                #pragma unroll
                for (int jn = 0; jn < 2; jn++) {
                    bf16x8 bfrag = *(const bf16x8*)(kl +
                        ((((jn * 16 + row) * 256) + kf * 32 + quad * 8) ^ kxor));
                    #pragma unroll
                    for (int mi = 0; mi < 2; mi++)
                        sf[mi][jn] = __builtin_amdgcn_mfma_f32_16x16x32_bf16(
                            qf[mi][kf], bfrag, sf[mi][jn], 0, 0, 0);
                }
            __builtin_amdgcn_s_setprio(0);

            int kk0 = kt * 32;
            bool diag = (kt == wlast);     // only the diagonal tile masks
            if (diag) {
                #pragma unroll
                for (int mi = 0; mi < 2; mi++)
                    #pragma unroll
                    for (int jn = 0; jn < 2; jn++)
                        #pragma unroll
                        for (int r = 0; r < 4; r++)
                            if (kk0 + jn * 16 + row >
                                qrowbase + mi * 16 + quad * 4 + r)
                                sf[mi][jn][r] = MASKV;
            }

            // online softmax with defer-max (THR=8); DPP reduces (VALU pipe)
            float pmax[2][4];
            int need = 0;
            #pragma unroll
            for (int mi = 0; mi < 2; mi++)
                #pragma unroll
                for (int r = 0; r < 4; r++) {
                    pmax[mi][r] = red16_max(fmaxf(sf[mi][0][r], sf[mi][1][r]));
                    need |= (pmax[mi][r] > m_i[mi][r] + 8.0f) ? 1 : 0;
                }
            if (__any(need)) {
                #pragma unroll
                for (int mi = 0; mi < 2; mi++)
                    #pragma unroll
                    for (int r = 0; r < 4; r++) {
                        float mnew = fmaxf(m_i[mi][r], pmax[mi][r]);
                        float al = __expf(m_i[mi][r] - mnew);
                        m_i[mi][r] = mnew;
                        l_i[mi][r] *= al;
                        #pragma unroll
                        for (int n = 0; n < 16; n++) o[mi][n][r] *= al;
                    }
            }
            #pragma unroll
            for (int mi = 0; mi < 2; mi++)
                #pragma unroll
                for (int r = 0; r < 4; r++) {
                    float ps = 0.0f;
                    #pragma unroll
                    for (int jn = 0; jn < 2; jn++) {
                        sf[mi][jn][r] = __expf(sf[mi][jn][r] - m_i[mi][r]);
                        ps += sf[mi][jn][r];
                    }
                    l_i[mi][r] += red16_sum(ps);
                }

            // P: C-layout -> wave-private LDS -> A-layout (2 frags, K=32)
            u16* pw = p_lds[wave];
            #pragma unroll
            for (int mi = 0; mi < 2; mi++)
                #pragma unroll
                for (int jn = 0; jn < 2; jn++)
                    #pragma unroll
                    for (int r = 0; r < 4; r++)
                        pw[(mi * 16 + quad * 4 + r) * 40 + jn * 16 + row] =
                            f2bf(sf[mi][jn][r]);
            bf16x8 pf0 = *(const bf16x8*)(pw + row * 40 + quad * 8);
            bf16x8 pf1 = *(const bf16x8*)(pw + (16 + row) * 40 + quad * 8);

            // O += P V  (V frag read once, used by both m-frags)
            __builtin_amdgcn_s_setprio(1);
            #pragma unroll
            for (int n = 0; n < 16; n++) {
                bf16x8 bv = *(const bf16x8*)(vl +
                    ((((n * 16 + row) * 32) + quad * 8) ^ vxor));
                o[0][n] = __builtin_amdgcn_mfma_f32_16x16x32_bf16(pf0, bv, o[0][n], 0, 0, 0);
                o[1][n] = __builtin_amdgcn_mfma_f32_16x16x32_bf16(pf1, bv, o[1][n], 0, 0, 0);
            }
            __builtin_amdgcn_s_setprio(0);
        }
        __syncthreads();   // vmcnt(0): prefetched tile landed; buffers swap
    }

    if (pi == 255) {
        // full-range chunk: normalize and store final bf16
        u16* aob = ao + (((size_t)b << 10) + qrowbase) * 256;
        #pragma unroll
        for (int mi = 0; mi < 2; mi++)
            #pragma unroll
            for (int r = 0; r < 4; r++) {
                float inv = 1.0f / l_i[mi][r];
                #pragma unroll
                for (int n = 0; n < 16; n++)
                    aob[(size_t)(mi * 16 + quad * 4 + r) * 256 + n * 16 + row] =
                        f2bf(o[mi][n][r] * inv);
            }
    } else {
        // split chunk: write unnormalized O col-major [col][128 rows] + (m,l)
        u16* pb = part + ((size_t)(b * 13 + pi) << 15);
        int rbase = wave * 32 + quad * 4;
        #pragma unroll
        for (int mi = 0; mi < 2; mi++)
            #pragma unroll
            for (int n = 0; n < 16; n++) {
                ushort4 pk;
                pk.x = f2bf(o[mi][n][0]);
                pk.y = f2bf(o[mi][n][1]);
                pk.z = f2bf(o[mi][n][2]);
                pk.w = f2bf(o[mi][n][3]);
                *(ushort4*)(pb + (size_t)(n * 16 + row) * 128 + rbase + mi * 16) = pk;
            }
        if (row == 0) {
            #pragma unroll
            for (int mi = 0; mi < 2; mi++)
                #pragma unroll
                for (int r = 0; r < 4; r++) {
                    int rt = wave * 32 + mi * 16 + quad * 4 + r;
                    float2 v2; v2.x = m_i[mi][r]; v2.y = l_i[mi][r];
                    *(float2*)(ml + ((size_t)((b * 13 + pi) * 128 + rt)) * 2) = v2;
                }
        }
    }
}

// Merge 2-4 k-range chunk partials per split q-tile (qt 3..7).
// Partials are col-major [256 cols][128 rows]; thread = col, rows contiguous.
__constant__ unsigned char SP_PB[5] = {0, 2, 4, 6, 9};
__constant__ unsigned char SP_NC[5] = {2, 2, 2, 3, 4};

__global__ __launch_bounds__(256) void attn_merge(
    const u16* __restrict__ part, const float* __restrict__ ml,
    u16* __restrict__ ao) {
    __shared__ float s_sc[4][128];
    int j = blockIdx.x;                  // 0..159 = b*5 + t
    int b = j / 5, t = j - b * 5;
    int pb0 = SP_PB[t], nc = SP_NC[t];
    int tid = threadIdx.x;
    if (tid < 128) {
        int r = tid;
        float mm[4], lv[4];
        float mx = -1e30f;
        for (int cc = 0; cc < nc; cc++) {
            const float* p2 = ml + ((size_t)((b * 13 + pb0 + cc) * 128 + r)) * 2;
            mm[cc] = p2[0]; lv[cc] = p2[1];
            mx = fmaxf(mx, mm[cc]);
        }
        float lsum = 0.0f;
        for (int cc = 0; cc < nc; cc++) {
            mm[cc] = __expf(mm[cc] - mx);
            lsum += lv[cc] * mm[cc];
        }
        float inv = 1.0f / lsum;
        for (int cc = 0; cc < nc; cc++) s_sc[cc][r] = mm[cc] * inv;
    }
    __syncthreads();
    int col = tid;
    const u16* pc[4];
    for (int cc = 0; cc < 4; cc++)
        pc[cc] = part + ((size_t)(b * 13 + pb0 + (cc < nc ? cc : 0)) << 15)
               + (size_t)col * 128;
    u16* dst = ao + ((size_t)((b << 10) + (t + 3) * 128)) * 256 + col;
    for (int u = 0; u < 16; u++) {       // 8 rows per group
        float acc[8];
        #pragma unroll
        for (int e = 0; e < 8; e++) acc[e] = 0.0f;
        for (int cc = 0; cc < nc; cc++) {
            U8 v; v.v = *(const uint4*)(pc[cc] + u * 8);
            #pragma unroll
            for (int e = 0; e < 8; e++)
                acc[e] += s_sc[cc][u * 8 + e] * bf2f(v.s[e]);
        }
        #pragma unroll
        for (int e = 0; e < 8; e++)
            dst[(size_t)(u * 8 + e) * 256] = f2bf(acc[e]);
    }
}

// ---------------------------------------------------------------------------
extern "C" void kernel_launch(void* const* d_in, const int* in_sizes, int n_in,
                              void* d_out, int out_size, void* d_ws, size_t ws_size,
                              hipStream_t stream) {
    const float* x      = (const float*)d_in[0];
    const float* ln1_s  = (const float*)d_in[1];
    const float* ln1_b  = (const float*)d_in[2];
    const float* w_qkv  = (const float*)d_in[3];
    const float* b_qkv  = (const float*)d_in[4];
    const float* w_proj = (const float*)d_in[5];
    const float* b_proj = (const float*)d_in[6];
    const float* ln2_s  = (const float*)d_in[7];
    const float* ln2_b  = (const float*)d_in[8];
    const float* w_fc1  = (const float*)d_in[9];
    const float* b_fc1  = (const float*)d_in[10];
    const float* w_fc2  = (const float*)d_in[11];
    const float* b_fc2  = (const float*)d_in[12];
    float* out = (float*)d_out;

    // d_out reuse timeline:
    //   ln1 -> h (first 16.8MB) -> consumed by gemm_qkv
    //   attn partials: 27.3MB col-major bf16 from d_out base + (m,l) 426KB at
    //   float offset 7.2M (28.8MB) -> consumed by attn_merge
    //   ln2 -> h2 (second 16.8MB, overwrites dead partial tail)
    //   fc2 -> overwrites all of d_out last.
    u16* h  = (u16*)d_out;                     // LN1(x)
    u16* h2 = h + (size_t)NROWS * 256;         // LN2(x2)

    u16* W = (u16*)d_ws;
    u16* wqkvT  = W;                           // 768*256
    u16* wprojT = wqkvT + 196608;              // 256*256
    u16* wfc1T  = wprojT + 65536;              // 128*256
    u16* wfc2T  = wfc1T + 32768;               // 256*128
    u16* buf1   = wfc2T + 32768;               // q, then attn-out (in place)
    u16* buf2   = buf1 + (size_t)NROWS * 256;  // k, then x2
    u16* buf3   = buf2 + (size_t)NROWS * 256;  // vT, then a1

    u16*   part  = (u16*)d_out;                // attn partial O (bf16, col-major)
    float* mlbuf = (float*)d_out + 7200000;    // attn partial (m,l)

    transpose_weights<<<dim3(64), dim3(256), 0, stream>>>(
        w_qkv, wqkvT, w_proj, wprojT, w_fc1, wfc1T, w_fc2, wfc2T);
    ln_fused<float><<<dim3(NROWS / 4), dim3(256), 0, stream>>>(
        x, ln1_s, ln1_b, h);
    gemm_qkv<<<dim3(NROWS / 128, 12), dim3(256), 0, stream>>>(
        h, wqkvT, b_qkv, buf1, buf2, buf3);
    attn_kernel<<<dim3(512), dim3(256), 0, stream>>>(
        buf1, buf2, buf3, buf1, part, mlbuf);
    attn_merge<<<dim3(160), dim3(256), 0, stream>>>(
        part, mlbuf, buf1);
    gemm_proj<<<dim3(NROWS / 128, 4), dim3(256), 0, stream>>>(
        buf1, wprojT, b_proj, x, buf2);
    ln_fused<u16><<<dim3(NROWS / 4), dim3(256), 0, stream>>>(
        buf2, ln2_s, ln2_b, h2);
    gemm_fc1<<<dim3(NROWS / 128, 2), dim3(256), 0, stream>>>(
        h2, wfc1T, b_fc1, buf3);
    gemm_fc2<<<dim3(NROWS / 128, 4), dim3(256), 0, stream>>>(
        buf3, wfc2T, b_fc2, buf2, out);
}

// Round 5
// 251.729 us; speedup vs baseline: 1.4788x; 1.3577x over previous
//
#include <hip/hip_runtime.h>
#include <hip/hip_bf16.h>

#define D_MODEL 256
#define D_HID   128
#define SEQ     1024
#define NBATCH  32
#define NROWS   (NBATCH * SEQ)    // 32768
#define MASKV   -10000.0f
#define EPSLN   1e-5f

typedef unsigned short u16;
using bf16x8 = __attribute__((ext_vector_type(8))) short;
using f32x4  = __attribute__((ext_vector_type(4))) float;

union U8 { uint4 v; u16 s[8]; };

__device__ __forceinline__ float bf2f(u16 u) {
    unsigned int x = ((unsigned int)u) << 16;
    return __uint_as_float(x);
}
__device__ __forceinline__ u16 f2bf(float f) {
    unsigned int u = __float_as_uint(f);
    u += 0x7fff + ((u >> 16) & 1);   // RNE
    return (u16)(u >> 16);
}
__device__ __forceinline__ void load4(const float* p, float* f) {
    float4 a = *(const float4*)p;
    f[0] = a.x; f[1] = a.y; f[2] = a.z; f[3] = a.w;
}
__device__ __forceinline__ void load4(const u16* p, float* f) {
    ushort4 v = *(const ushort4*)p;
    f[0] = bf2f(v.x); f[1] = bf2f(v.y); f[2] = bf2f(v.z); f[3] = bf2f(v.w);
}
// async global->LDS, 16B per lane; LDS dest = wave-uniform base + lane*16
__device__ __forceinline__ void gload16(const u16* g, u16* l) {
    __builtin_amdgcn_global_load_lds(
        (const __attribute__((address_space(1))) void*)g,
        (__attribute__((address_space(3))) void*)l, 16, 0, 0);
}

// DPP cross-lane: VALU-pipe butterfly over the 16 'row' lanes.
template <int CTRL>
__device__ __forceinline__ float dpp_mov(float v) {
    return __int_as_float(__builtin_amdgcn_update_dpp(
        0, __float_as_int(v), CTRL, 0xf, 0xf, true));
}
__device__ __forceinline__ float red16_max(float v) {
    v = fmaxf(v, dpp_mov<0xB1>(v));
    v = fmaxf(v, dpp_mov<0x4E>(v));
    v = fmaxf(v, dpp_mov<0x141>(v));
    v = fmaxf(v, dpp_mov<0x140>(v));
    return v;
}
__device__ __forceinline__ float red16_sum(float v) {
    v += dpp_mov<0xB1>(v);
    v += dpp_mov<0x4E>(v);
    v += dpp_mov<0x141>(v);
    v += dpp_mov<0x140>(v);
    return v;
}

// ---------------------------------------------------------------------------
// Weight transposes: fp32 W[K][N] -> bf16 WT[N][K]
// ---------------------------------------------------------------------------
__global__ __launch_bounds__(256) void transpose_weights(
    const float* __restrict__ wqkv, u16* __restrict__ wqkvT,
    const float* __restrict__ wproj, u16* __restrict__ wprojT,
    const float* __restrict__ wfc1, u16* __restrict__ wfc1T,
    const float* __restrict__ wfc2, u16* __restrict__ wfc2T) {
    int tid = blockIdx.x * 256 + threadIdx.x;
    int stride = gridDim.x * 256;
    for (int i = tid; i < 768 * 256; i += stride) {
        int n = i >> 8, k = i & 255;
        wqkvT[i] = f2bf(wqkv[k * 768 + n]);
    }
    for (int i = tid; i < 256 * 256; i += stride) {
        int n = i >> 8, k = i & 255;
        wprojT[i] = f2bf(wproj[k * 256 + n]);
    }
    for (int i = tid; i < 128 * 256; i += stride) {
        int n = i >> 8, k = i & 255;
        wfc1T[i] = f2bf(wfc1[k * 128 + n]);
    }
    for (int i = tid; i < 256 * 128; i += stride) {
        int n = i >> 7, k = i & 127;
        wfc2T[i] = f2bf(wfc2[k * 256 + n]);
    }
}

// ---------------------------------------------------------------------------
// Fused LayerNorm: one wave per row (256 cols, 4/lane), writes bf16 row.
// ---------------------------------------------------------------------------
template <typename TX>
__global__ __launch_bounds__(256) void ln_fused(
    const TX* __restrict__ x, const float* __restrict__ gamma,
    const float* __restrict__ beta, u16* __restrict__ out) {
    int wave = threadIdx.x >> 6, lane = threadIdx.x & 63;
    int row = blockIdx.x * 4 + wave;
    float f[4];
    load4(x + (size_t)row * D_MODEL + lane * 4, f);
    float s  = f[0] + f[1] + f[2] + f[3];
    float sq = f[0] * f[0] + f[1] * f[1] + f[2] * f[2] + f[3] * f[3];
    #pragma unroll
    for (int off = 1; off < 64; off <<= 1) {
        s  += __shfl_xor(s, off);
        sq += __shfl_xor(sq, off);
    }
    float mu   = s * (1.0f / 256.0f);
    float var  = sq * (1.0f / 256.0f) - mu * mu;
    float rstd = rsqrtf(var + EPSLN);
    float g[4], be[4];
    load4(gamma + lane * 4, g);
    load4(beta + lane * 4, be);
    ushort4 o;
    o.x = f2bf((f[0] - mu) * rstd * g[0] + be[0]);
    o.y = f2bf((f[1] - mu) * rstd * g[1] + be[1]);
    o.z = f2bf((f[2] - mu) * rstd * g[2] + be[2]);
    o.w = f2bf((f[3] - mu) * rstd * g[3] + be[3]);
    *(ushort4*)(out + (size_t)row * D_MODEL + lane * 4) = o;
}

// ---------------------------------------------------------------------------
// 128x128 GEMM tile mainloop (m97-class): single 64-KB LDS buffer, staged via
// global_load_lds width-16 with inverse-XOR-swizzled GLOBAL source (rule #21);
// ds_read_b128 frag reads apply the same XOR -> 2-way (free) bank aliasing.
// 4 waves in 2x2, each owns a 64x64 quadrant (acc[4][4]). Grid: m-tile fast ->
// A-tile x pinned to XCD x%8 across all n-columns (L2-local A reuse).
// ---------------------------------------------------------------------------
#define GT2_ELEMS (2 * 128 * 128)   // A tile + B tile, 64 KB

template <int K>
__device__ __forceinline__ void gemm_tile2(
    const u16* __restrict__ A, const u16* __restrict__ BT,
    int m0, int n0, u16* lds, f32x4 acc[4][4]) {
    u16* ldsA = lds;
    u16* ldsB = lds + 128 * 128;
    const int tid = threadIdx.x;
    const int lane = tid & 63, wave = tid >> 6;
    const int wr = (wave >> 1) * 64, wc = (wave & 1) * 64;
    const int row = lane & 15, quad = lane >> 4;

    for (int ks = 0; ks < K; ks += 128) {
        __syncthreads();
        #pragma unroll
        for (int i = 0; i < 8; i++) {
            int blk = i * 4 + wave;               // 1-KB block 0..31
            int B = (blk << 10) + lane * 16;      // byte offset in 32-KB tile
            int r = B >> 8;                       // tile row (256-B rows)
            int cb = (B & 255) ^ ((r & 7) << 4);  // inverse-swizzled byte col
            gload16(A + (size_t)(m0 + r) * K + ks + (cb >> 1),
                    ldsA + (blk << 9));
            gload16(BT + (size_t)(n0 + r) * K + ks + (cb >> 1),
                    ldsB + (blk << 9));
        }
        __syncthreads();
        #pragma unroll
        for (int k0 = 0; k0 < 128; k0 += 32) {
            bf16x8 a[4], b[4];
            #pragma unroll
            for (int mi = 0; mi < 4; mi++) {
                int rr = wr + mi * 16 + row;
                a[mi] = *(const bf16x8*)(ldsA + rr * 128 +
                         ((k0 + quad * 8) ^ ((rr & 7) << 3)));
            }
            #pragma unroll
            for (int nj = 0; nj < 4; nj++) {
                int rr = wc + nj * 16 + row;
                b[nj] = *(const bf16x8*)(ldsB + rr * 128 +
                         ((k0 + quad * 8) ^ ((rr & 7) << 3)));
            }
            #pragma unroll
            for (int mi = 0; mi < 4; mi++)
                #pragma unroll
                for (int nj = 0; nj < 4; nj++)
                    acc[mi][nj] = __builtin_amdgcn_mfma_f32_16x16x32_bf16(
                        a[mi], b[nj], acc[mi][nj], 0, 0, 0);
        }
    }
}

#define ZERO_ACC4(acc)                                       \
    _Pragma("unroll") for (int i_ = 0; i_ < 4; i_++)         \
    _Pragma("unroll") for (int j_ = 0; j_ < 4; j_++)         \
    _Pragma("unroll") for (int e_ = 0; e_ < 4; e_++) acc[i_][j_][e_] = 0.0f;

#define EPILOG_IDX4                                          \
    int lane = threadIdx.x & 63, wave = threadIdx.x >> 6;    \
    int wr = (wave >> 1) * 64, wc = (wave & 1) * 64;         \
    int row = lane & 15, quad = lane >> 4;

// QKV: h @ wqkv + b -> q (pre-scaled 1/16), k, vT[b,256,s]
__global__ __launch_bounds__(256) void gemm_qkv(
    const u16* __restrict__ h, const u16* __restrict__ wqkvT,
    const float* __restrict__ b_qkv,
    u16* __restrict__ q, u16* __restrict__ kk, u16* __restrict__ vT) {
    __shared__ u16 lds[GT2_ELEMS];
    f32x4 acc[4][4];
    ZERO_ACC4(acc)
    int m0 = blockIdx.x * 128, n0 = blockIdx.y * 128;
    gemm_tile2<256>(h, wqkvT, m0, n0, lds, acc);
    EPILOG_IDX4
    #pragma unroll
    for (int mi = 0; mi < 4; mi++) {
        #pragma unroll
        for (int nj = 0; nj < 4; nj++) {
            int gn = n0 + wc + nj * 16 + row;
            float bias = b_qkv[gn];
            int gm = m0 + wr + mi * 16 + quad * 4;
            if (gn < 256) {          // q, pre-scaled by 1/sqrt(D)=1/16
                #pragma unroll
                for (int r = 0; r < 4; r++)
                    q[(size_t)(gm + r) * 256 + gn] =
                        f2bf((acc[mi][nj][r] + bias) * 0.0625f);
            } else if (gn < 512) {   // k
                int col = gn - 256;
                #pragma unroll
                for (int r = 0; r < 4; r++)
                    kk[(size_t)(gm + r) * 256 + col] = f2bf(acc[mi][nj][r] + bias);
            } else {                 // v -> vT[b][d][s]
                int d = gn - 512;
                int b = gm >> 10, s = gm & 1023;
                ushort4 pack;
                pack.x = f2bf(acc[mi][nj][0] + bias);
                pack.y = f2bf(acc[mi][nj][1] + bias);
                pack.z = f2bf(acc[mi][nj][2] + bias);
                pack.w = f2bf(acc[mi][nj][3] + bias);
                *(ushort4*)(vT + ((size_t)(b * 256 + d) << 10) + s) = pack;
            }
        }
    }
}

// proj: ao @ wproj + b + residual(x fp32) -> x2 (bf16)
__global__ __launch_bounds__(256) void gemm_proj(
    const u16* __restrict__ ao, const u16* __restrict__ wprojT,
    const float* __restrict__ b_proj, const float* __restrict__ x_in,
    u16* __restrict__ x2) {
    __shared__ u16 lds[GT2_ELEMS];
    f32x4 acc[4][4];
    ZERO_ACC4(acc)
    int m0 = blockIdx.x * 128, n0 = blockIdx.y * 128;
    gemm_tile2<256>(ao, wprojT, m0, n0, lds, acc);
    EPILOG_IDX4
    #pragma unroll
    for (int mi = 0; mi < 4; mi++)
        #pragma unroll
        for (int nj = 0; nj < 4; nj++) {
            int gn = n0 + wc + nj * 16 + row;
            float bias = b_proj[gn];
            int gm = m0 + wr + mi * 16 + quad * 4;
            #pragma unroll
            for (int r = 0; r < 4; r++) {
                size_t idx = (size_t)(gm + r) * 256 + gn;
                x2[idx] = f2bf(acc[mi][nj][r] + bias + x_in[idx]);
            }
        }
}

// fc1: h2 @ wfc1 + b, ReLU -> a1
__global__ __launch_bounds__(256) void gemm_fc1(
    const u16* __restrict__ h2, const u16* __restrict__ wfc1T,
    const float* __restrict__ b_fc1, u16* __restrict__ a1) {
    __shared__ u16 lds[GT2_ELEMS];
    f32x4 acc[4][4];
    ZERO_ACC4(acc)
    int m0 = blockIdx.x * 128, n0 = 0;
    gemm_tile2<256>(h2, wfc1T, m0, n0, lds, acc);
    EPILOG_IDX4
    #pragma unroll
    for (int mi = 0; mi < 4; mi++)
        #pragma unroll
        for (int nj = 0; nj < 4; nj++) {
            int gn = wc + nj * 16 + row;
            float bias = b_fc1[gn];
            int gm = m0 + wr + mi * 16 + quad * 4;
            #pragma unroll
            for (int r = 0; r < 4; r++) {
                float v = acc[mi][nj][r] + bias;
                a1[(size_t)(gm + r) * 128 + gn] = f2bf(fmaxf(v, 0.0f));
            }
        }
}

// fc2: a1 @ wfc2 + b + residual(x2) -> out (fp32)
__global__ __launch_bounds__(256) void gemm_fc2(
    const u16* __restrict__ a1, const u16* __restrict__ wfc2T,
    const float* __restrict__ b_fc2, const u16* __restrict__ x2,
    float* __restrict__ out) {
    __shared__ u16 lds[GT2_ELEMS];
    f32x4 acc[4][4];
    ZERO_ACC4(acc)
    int m0 = blockIdx.x * 128, n0 = blockIdx.y * 128;
    gemm_tile2<128>(a1, wfc2T, m0, n0, lds, acc);
    EPILOG_IDX4
    #pragma unroll
    for (int mi = 0; mi < 4; mi++)
        #pragma unroll
        for (int nj = 0; nj < 4; nj++) {
            int gn = n0 + wc + nj * 16 + row;
            float bias = b_fc2[gn];
            int gm = m0 + wr + mi * 16 + quad * 4;
            #pragma unroll
            for (int r = 0; r < 4; r++) {
                size_t idx = (size_t)(gm + r) * 256 + gn;
                out[idx] = acc[mi][nj][r] + bias + bf2f(x2[idx]);
            }
        }
}

// ---------------------------------------------------------------------------
// Flash attention v5 (REVERT to round-2 kernel, measured 74.5 us):
// 64 q-rows/block, 4 waves x 16 rows. 24 work items per batch, LPT-ordered;
// qt 0..7 whole; qt 8..15 two k-range halves writing (m,l,O) partials.
// Grid 768 = backfill over 512 resident slots. b = j&31 -> XCD-local batches.
// ---------------------------------------------------------------------------
__constant__ unsigned char WQT[24] = {7,15,15,14,14,6,13,13,12,12,5,11,
                                      11,10,10,4,9,9,8,8,3,2,1,0};
__constant__ unsigned char WH[24]  = {2,0,1,0,1,2,0,1,0,1,2,0,
                                      1,0,1,2,0,1,0,1,2,2,2,2};

__global__ __launch_bounds__(256) void attn_kernel(
    const u16* __restrict__ q, const u16* __restrict__ k,
    const u16* __restrict__ vT, u16* __restrict__ ao,
    u16* __restrict__ part, float* __restrict__ ml) {
    __shared__ u16 k_lds[2][32 * 256];   // 2 x 16 KB, K tile [s][d]
    __shared__ u16 v_lds[2][256 * 32];   // 2 x 16 KB, V^T tile [d][s]
    __shared__ u16 p_lds[4][16 * 40];    // 5 KB, wave-private P staging

    int j = blockIdx.x;
    int b = j & 31, w = j >> 5;          // w 0..23, LPT-ordered
    int qt = WQT[w], hh = WH[w];
    int lo, hi;
    if (hh == 2) { lo = 0; hi = 2 * qt + 2; }
    else         { lo = hh * (qt + 1); hi = lo + qt + 1; }

    int tid = threadIdx.x;
    int lane = tid & 63, wave = tid >> 6;
    int row = lane & 15, quad = lane >> 4;
    int q0 = qt * 64;
    int qrow0 = q0 + wave * 16;

    const u16* qb = q + ((size_t)b << 10) * 256;
    const u16* kb = k + ((size_t)b << 10) * 256;
    const u16* vb = vT + (((size_t)b * 256) << 10);

    const int kxor = (row & 7) << 3;   // u16-unit XOR for K reads
    const int vxor = (row & 6) << 2;   // u16-unit XOR for V reads

    // Q fragments held in registers for the whole kernel (pre-scaled by 1/16)
    bf16x8 qf[8];
    #pragma unroll
    for (int kf = 0; kf < 8; kf++)
        qf[kf] = *(const bf16x8*)(qb + (size_t)(qrow0 + row) * 256 + kf * 32 + quad * 8);

    f32x4 o[16];
    #pragma unroll
    for (int n = 0; n < 16; n++)
        #pragma unroll
        for (int e = 0; e < 4; e++) o[n][e] = 0.0f;
    float m_i[4], l_i[4];
    #pragma unroll
    for (int r = 0; r < 4; r++) { m_i[r] = -1e30f; l_i[r] = 0.0f; }

    int wlast = 2 * qt + (wave >> 1);    // last k-tile this wave computes

    auto stage = [&](int bf, int kt) {
        int k0 = kt << 5;
        #pragma unroll
        for (int c = 0; c < 4; c++) {
            int blk = wave * 4 + c;
            int B = (blk << 10) + lane * 16;          // byte offset in 16KB tile
            // K: 32 rows x 512 B
            int rk = B >> 9;
            int ck = (B & 511) ^ ((rk & 7) << 4);
            gload16(kb + (size_t)(k0 + rk) * 256 + (ck >> 1),
                    &k_lds[bf][blk << 9]);
            // V^T: 256 rows x 64 B
            int rv = B >> 6;
            int cv = (B & 63) ^ ((rv & 6) << 3);
            gload16(vb + ((size_t)rv << 10) + k0 + (cv >> 1),
                    &v_lds[bf][blk << 9]);
        }
    };

    stage(0, lo);
    __syncthreads();                       // vmcnt(0) drain + barrier

    for (int kt = lo; kt < hi; kt++) {
        int cur = (kt - lo) & 1;
        if (kt + 1 < hi) stage(cur ^ 1, kt + 1);   // prefetch next tile
        if (kt <= wlast) {
            const u16* kl = k_lds[cur];
            const u16* vl = v_lds[cur];

            // S = Q K^T : 16 x 32
            f32x4 sf[2];
            #pragma unroll
            for (int jn = 0; jn < 2; jn++)
                #pragma unroll
                for (int e = 0; e < 4; e++) sf[jn][e] = 0.0f;
            __builtin_amdgcn_s_setprio(1);
            #pragma unroll
            for (int kf = 0; kf < 8; kf++)
                #pragma unroll
                for (int jn = 0; jn < 2; jn++) {
                    bf16x8 bfrag = *(const bf16x8*)(kl +
                        ((((jn * 16 + row) * 256) + kf * 32 + quad * 8) ^ kxor));
                    sf[jn] = __builtin_amdgcn_mfma_f32_16x16x32_bf16(
                        qf[kf], bfrag, sf[jn], 0, 0, 0);
                }
            __builtin_amdgcn_s_setprio(0);

            int kk0 = kt * 32;
            bool diag = (kt == wlast);     // only the diagonal tile masks
            int qrow = qrow0 + quad * 4;
            float sv[2][4];
            #pragma unroll
            for (int jn = 0; jn < 2; jn++)
                #pragma unroll
                for (int r = 0; r < 4; r++) {
                    float v = sf[jn][r];
                    if (diag && (kk0 + jn * 16 + row > qrow + r)) v = MASKV;
                    sv[jn][r] = v;
                }

            // online softmax with defer-max (THR=8); DPP reduces (VALU pipe)
            float pmax[4];
            int need = 0;
            #pragma unroll
            for (int r = 0; r < 4; r++) {
                pmax[r] = red16_max(fmaxf(sv[0][r], sv[1][r]));
                need |= (pmax[r] > m_i[r] + 8.0f) ? 1 : 0;
            }
            if (__any(need)) {
                #pragma unroll
                for (int r = 0; r < 4; r++) {
                    float mnew = fmaxf(m_i[r], pmax[r]);
                    float al = __expf(m_i[r] - mnew);
                    m_i[r] = mnew;
                    l_i[r] *= al;
                    #pragma unroll
                    for (int n = 0; n < 16; n++) o[n][r] *= al;
                }
            }
            #pragma unroll
            for (int r = 0; r < 4; r++) {
                float ps = 0.0f;
                #pragma unroll
                for (int jn = 0; jn < 2; jn++) {
                    sv[jn][r] = __expf(sv[jn][r] - m_i[r]);
                    ps += sv[jn][r];
                }
                l_i[r] += red16_sum(ps);
            }

            // P: C-layout -> wave-private LDS -> A-layout (one frag, K=32)
            u16* pw = p_lds[wave];
            #pragma unroll
            for (int jn = 0; jn < 2; jn++)
                #pragma unroll
                for (int r = 0; r < 4; r++)
                    pw[(quad * 4 + r) * 40 + jn * 16 + row] = f2bf(sv[jn][r]);
            bf16x8 pf = *(const bf16x8*)(pw + row * 40 + quad * 8);

            // O += P V
            __builtin_amdgcn_s_setprio(1);
            #pragma unroll
            for (int n = 0; n < 16; n++) {
                bf16x8 bv = *(const bf16x8*)(vl +
                    ((((n * 16 + row) * 32) + quad * 8) ^ vxor));
                o[n] = __builtin_amdgcn_mfma_f32_16x16x32_bf16(pf, bv, o[n], 0, 0, 0);
            }
            __builtin_amdgcn_s_setprio(0);
        }
        __syncthreads();   // vmcnt(0): prefetched tile landed; buffers swap
    }

    if (hh == 2) {
        // full block: normalize and store final bf16
        float inv[4];
        #pragma unroll
        for (int r = 0; r < 4; r++) inv[r] = 1.0f / l_i[r];
        u16* aob = ao + (((size_t)b << 10) + qrow0) * 256;
        #pragma unroll
        for (int r = 0; r < 4; r++)
            #pragma unroll
            for (int n = 0; n < 16; n++)
                aob[(size_t)(quad * 4 + r) * 256 + n * 16 + row] =
                    f2bf(o[n][r] * inv[r]);
    } else {
        // split half: write unnormalized O (bf16) + per-row (m,l)
        int p = (((b << 3) | (qt - 8)) << 1) | hh;
        u16* pb = part + (((size_t)p) << 6) * 256;
        #pragma unroll
        for (int r = 0; r < 4; r++) {
            int rt = wave * 16 + quad * 4 + r;
            #pragma unroll
            for (int n = 0; n < 16; n++)
                pb[(size_t)rt * 256 + n * 16 + row] = f2bf(o[n][r]);
        }
        if (row == 0) {
            #pragma unroll
            for (int r = 0; r < 4; r++) {
                int rt = wave * 16 + quad * 4 + r;
                float2 v2; v2.x = m_i[r]; v2.y = l_i[r];
                *(float2*)(ml + ((size_t)((p << 6) + rt)) * 2) = v2;
            }
        }
    }
}

// Merge the two k-range halves for qt 8..15: standard (m,l,O) combine.
__global__ __launch_bounds__(256) void attn_merge(
    const u16* __restrict__ part, const float* __restrict__ ml,
    u16* __restrict__ ao) {
    int j = blockIdx.x;                  // 0..255 : b*8 + (qt-8)
    int b = j >> 3, qi = j & 7;
    int t = threadIdx.x;
    int r = t >> 2, cq = t & 3;          // row 0..63, col-quarter 0..3
    int pA = j << 1, pB = pA | 1;
    const float* mlA = ml + ((size_t)(pA << 6) + r) * 2;
    const float* mlB = ml + ((size_t)(pB << 6) + r) * 2;
    float mA = mlA[0], lA = mlA[1];
    float mB = mlB[0], lB = mlB[1];
    float m  = fmaxf(mA, mB);
    float eA = __expf(mA - m), eB = __expf(mB - m);
    float inv = 1.0f / (lA * eA + lB * eB);
    float sA = eA * inv, sB = eB * inv;
    const u16* oA = part + (((size_t)(pA << 6) + r) * 256) + cq * 64;
    const u16* oB = part + (((size_t)(pB << 6) + r) * 256) + cq * 64;
    u16* dst = ao + ((size_t)((b << 10) + 512 + (qi << 6) + r)) * 256 + cq * 64;
    #pragma unroll
    for (int u = 0; u < 8; u++) {
        U8 a, bb, o;
        a.v  = *(const uint4*)(oA + u * 8);
        bb.v = *(const uint4*)(oB + u * 8);
        #pragma unroll
        for (int e = 0; e < 8; e++)
            o.s[e] = f2bf(bf2f(a.s[e]) * sA + bf2f(bb.s[e]) * sB);
        *(uint4*)(dst + u * 8) = o.v;
    }
}

// ---------------------------------------------------------------------------
extern "C" void kernel_launch(void* const* d_in, const int* in_sizes, int n_in,
                              void* d_out, int out_size, void* d_ws, size_t ws_size,
                              hipStream_t stream) {
    const float* x      = (const float*)d_in[0];
    const float* ln1_s  = (const float*)d_in[1];
    const float* ln1_b  = (const float*)d_in[2];
    const float* w_qkv  = (const float*)d_in[3];
    const float* b_qkv  = (const float*)d_in[4];
    const float* w_proj = (const float*)d_in[5];
    const float* b_proj = (const float*)d_in[6];
    const float* ln2_s  = (const float*)d_in[7];
    const float* ln2_b  = (const float*)d_in[8];
    const float* w_fc1  = (const float*)d_in[9];
    const float* b_fc1  = (const float*)d_in[10];
    const float* w_fc2  = (const float*)d_in[11];
    const float* b_fc2  = (const float*)d_in[12];
    float* out = (float*)d_out;

    // d_out reuse: h (LN1 out) dies after gemm_qkv -> its 16.8MB region is
    // reused for attn split partials (exactly 512*64*256 bf16). The m,l array
    // (256KB) lives at the start of the h2 region, dead until ln2 runs (after
    // attn_merge has consumed it). fc2 overwrites d_out last.
    u16* h  = (u16*)d_out;                     // LN1(x), then attn partial O
    u16* h2 = h + (size_t)NROWS * 256;         // attn (m,l), then LN2(x2)

    u16* W = (u16*)d_ws;
    u16* wqkvT  = W;                           // 768*256
    u16* wprojT = wqkvT + 196608;              // 256*256
    u16* wfc1T  = wprojT + 65536;              // 128*256
    u16* wfc2T  = wfc1T + 32768;               // 256*128
    u16* buf1   = wfc2T + 32768;               // q, then attn-out (in place)
    u16* buf2   = buf1 + (size_t)NROWS * 256;  // k, then x2
    u16* buf3   = buf2 + (size_t)NROWS * 256;  // vT, then a1

    u16*   part  = h;                          // attn partial O (bf16)
    float* mlbuf = (float*)h2;                 // attn partial (m,l)

    transpose_weights<<<dim3(64), dim3(256), 0, stream>>>(
        w_qkv, wqkvT, w_proj, wprojT, w_fc1, wfc1T, w_fc2, wfc2T);
    ln_fused<float><<<dim3(NROWS / 4), dim3(256), 0, stream>>>(
        x, ln1_s, ln1_b, h);
    gemm_qkv<<<dim3(NROWS / 128, 6), dim3(256), 0, stream>>>(
        h, wqkvT, b_qkv, buf1, buf2, buf3);
    attn_kernel<<<dim3(768), dim3(256), 0, stream>>>(
        buf1, buf2, buf3, buf1, part, mlbuf);
    attn_merge<<<dim3(256), dim3(256), 0, stream>>>(
        part, mlbuf, buf1);
    gemm_proj<<<dim3(NROWS / 128, 2), dim3(256), 0, stream>>>(
        buf1, wprojT, b_proj, x, buf2);
    ln_fused<u16><<<dim3(NROWS / 4), dim3(256), 0, stream>>>(
        buf2, ln2_s, ln2_b, h2);
    gemm_fc1<<<dim3(NROWS / 128, 1), dim3(256), 0, stream>>>(
        h2, wfc1T, b_fc1, buf3);
    gemm_fc2<<<dim3(NROWS / 128, 2), dim3(256), 0, stream>>>(
        buf3, wfc2T, b_fc2, buf2, out);
}

// Round 6
// 250.800 us; speedup vs baseline: 1.4843x; 1.0037x over previous
//
#include <hip/hip_runtime.h>
#include <hip/hip_bf16.h>

#define D_MODEL 256
#define D_HID   128
#define SEQ     1024
#define NBATCH  32
#define NROWS   (NBATCH * SEQ)    // 32768
#define MASKV   -10000.0f
#define EPSLN   1e-5f

typedef unsigned short u16;
using bf16x8 = __attribute__((ext_vector_type(8))) short;
using f32x4  = __attribute__((ext_vector_type(4))) float;

union U8 { uint4 v; u16 s[8]; };

__device__ __forceinline__ float bf2f(u16 u) {
    unsigned int x = ((unsigned int)u) << 16;
    return __uint_as_float(x);
}
__device__ __forceinline__ u16 f2bf(float f) {
    unsigned int u = __float_as_uint(f);
    u += 0x7fff + ((u >> 16) & 1);   // RNE
    return (u16)(u >> 16);
}
__device__ __forceinline__ void load4(const float* p, float* f) {
    float4 a = *(const float4*)p;
    f[0] = a.x; f[1] = a.y; f[2] = a.z; f[3] = a.w;
}
__device__ __forceinline__ void load4(const u16* p, float* f) {
    ushort4 v = *(const ushort4*)p;
    f[0] = bf2f(v.x); f[1] = bf2f(v.y); f[2] = bf2f(v.z); f[3] = bf2f(v.w);
}
// async global->LDS, 16B per lane; LDS dest = wave-uniform base + lane*16
__device__ __forceinline__ void gload16(const u16* g, u16* l) {
    __builtin_amdgcn_global_load_lds(
        (const __attribute__((address_space(1))) void*)g,
        (__attribute__((address_space(3))) void*)l, 16, 0, 0);
}

// DPP cross-lane: VALU-pipe butterfly over 16-lane groups.
template <int CTRL>
__device__ __forceinline__ float dpp_mov(float v) {
    return __int_as_float(__builtin_amdgcn_update_dpp(
        0, __float_as_int(v), CTRL, 0xf, 0xf, true));
}
__device__ __forceinline__ float red16_max(float v) {
    v = fmaxf(v, dpp_mov<0xB1>(v));
    v = fmaxf(v, dpp_mov<0x4E>(v));
    v = fmaxf(v, dpp_mov<0x141>(v));
    v = fmaxf(v, dpp_mov<0x140>(v));
    return v;
}
__device__ __forceinline__ float red16_sum(float v) {
    v += dpp_mov<0xB1>(v);
    v += dpp_mov<0x4E>(v);
    v += dpp_mov<0x141>(v);
    v += dpp_mov<0x140>(v);
    return v;
}

// ---------------------------------------------------------------------------
// Weight transposes: fp32 W[K][N] -> bf16 WT[N][K]
// ---------------------------------------------------------------------------
__global__ __launch_bounds__(256) void transpose_weights(
    const float* __restrict__ wqkv, u16* __restrict__ wqkvT,
    const float* __restrict__ wproj, u16* __restrict__ wprojT,
    const float* __restrict__ wfc1, u16* __restrict__ wfc1T,
    const float* __restrict__ wfc2, u16* __restrict__ wfc2T) {
    int tid = blockIdx.x * 256 + threadIdx.x;
    int stride = gridDim.x * 256;
    for (int i = tid; i < 768 * 256; i += stride) {
        int n = i >> 8, k = i & 255;
        wqkvT[i] = f2bf(wqkv[k * 768 + n]);
    }
    for (int i = tid; i < 256 * 256; i += stride) {
        int n = i >> 8, k = i & 255;
        wprojT[i] = f2bf(wproj[k * 256 + n]);
    }
    for (int i = tid; i < 128 * 256; i += stride) {
        int n = i >> 8, k = i & 255;
        wfc1T[i] = f2bf(wfc1[k * 128 + n]);
    }
    for (int i = tid; i < 256 * 128; i += stride) {
        int n = i >> 7, k = i & 127;
        wfc2T[i] = f2bf(wfc2[k * 256 + n]);
    }
}

// ---------------------------------------------------------------------------
// Fused LayerNorm: one wave per row (256 cols, 4/lane), writes bf16 row.
// ---------------------------------------------------------------------------
template <typename TX>
__global__ __launch_bounds__(256) void ln_fused(
    const TX* __restrict__ x, const float* __restrict__ gamma,
    const float* __restrict__ beta, u16* __restrict__ out) {
    int wave = threadIdx.x >> 6, lane = threadIdx.x & 63;
    int row = blockIdx.x * 4 + wave;
    float f[4];
    load4(x + (size_t)row * D_MODEL + lane * 4, f);
    float s  = f[0] + f[1] + f[2] + f[3];
    float sq = f[0] * f[0] + f[1] * f[1] + f[2] * f[2] + f[3] * f[3];
    #pragma unroll
    for (int off = 1; off < 64; off <<= 1) {
        s  += __shfl_xor(s, off);
        sq += __shfl_xor(sq, off);
    }
    float mu   = s * (1.0f / 256.0f);
    float var  = sq * (1.0f / 256.0f) - mu * mu;
    float rstd = rsqrtf(var + EPSLN);
    float g[4], be[4];
    load4(gamma + lane * 4, g);
    load4(beta + lane * 4, be);
    ushort4 o;
    o.x = f2bf((f[0] - mu) * rstd * g[0] + be[0]);
    o.y = f2bf((f[1] - mu) * rstd * g[1] + be[1]);
    o.z = f2bf((f[2] - mu) * rstd * g[2] + be[2]);
    o.w = f2bf((f[3] - mu) * rstd * g[3] + be[3]);
    *(ushort4*)(out + (size_t)row * D_MODEL + lane * 4) = o;
}

// ---------------------------------------------------------------------------
// 128x128 GEMM tile mainloop (m97-class): single 64-KB LDS buffer, staged via
// global_load_lds width-16 with inverse-XOR-swizzled GLOBAL source (rule #21);
// ds_read_b128 frag reads apply the same XOR -> 2-way (free) bank aliasing.
// 4 waves in 2x2, each owns a 64x64 quadrant (acc[4][4]).
// ---------------------------------------------------------------------------
#define GT2_ELEMS (2 * 128 * 128)   // A tile + B tile, 64 KB

template <int K>
__device__ __forceinline__ void gemm_tile2(
    const u16* __restrict__ A, const u16* __restrict__ BT,
    int m0, int n0, u16* lds, f32x4 acc[4][4]) {
    u16* ldsA = lds;
    u16* ldsB = lds + 128 * 128;
    const int tid = threadIdx.x;
    const int lane = tid & 63, wave = tid >> 6;
    const int wr = (wave >> 1) * 64, wc = (wave & 1) * 64;
    const int row = lane & 15, quad = lane >> 4;

    for (int ks = 0; ks < K; ks += 128) {
        __syncthreads();
        #pragma unroll
        for (int i = 0; i < 8; i++) {
            int blk = i * 4 + wave;               // 1-KB block 0..31
            int B = (blk << 10) + lane * 16;      // byte offset in 32-KB tile
            int r = B >> 8;                       // tile row (256-B rows)
            int cb = (B & 255) ^ ((r & 7) << 4);  // inverse-swizzled byte col
            gload16(A + (size_t)(m0 + r) * K + ks + (cb >> 1),
                    ldsA + (blk << 9));
            gload16(BT + (size_t)(n0 + r) * K + ks + (cb >> 1),
                    ldsB + (blk << 9));
        }
        __syncthreads();
        #pragma unroll
        for (int k0 = 0; k0 < 128; k0 += 32) {
            bf16x8 a[4], b[4];
            #pragma unroll
            for (int mi = 0; mi < 4; mi++) {
                int rr = wr + mi * 16 + row;
                a[mi] = *(const bf16x8*)(ldsA + rr * 128 +
                         ((k0 + quad * 8) ^ ((rr & 7) << 3)));
            }
            #pragma unroll
            for (int nj = 0; nj < 4; nj++) {
                int rr = wc + nj * 16 + row;
                b[nj] = *(const bf16x8*)(ldsB + rr * 128 +
                         ((k0 + quad * 8) ^ ((rr & 7) << 3)));
            }
            #pragma unroll
            for (int mi = 0; mi < 4; mi++)
                #pragma unroll
                for (int nj = 0; nj < 4; nj++)
                    acc[mi][nj] = __builtin_amdgcn_mfma_f32_16x16x32_bf16(
                        a[mi], b[nj], acc[mi][nj], 0, 0, 0);
        }
    }
}

#define ZERO_ACC4(acc)                                       \
    _Pragma("unroll") for (int i_ = 0; i_ < 4; i_++)         \
    _Pragma("unroll") for (int j_ = 0; j_ < 4; j_++)         \
    _Pragma("unroll") for (int e_ = 0; e_ < 4; e_++) acc[i_][j_][e_] = 0.0f;

#define EPILOG_IDX4                                          \
    int lane = threadIdx.x & 63, wave = threadIdx.x >> 6;    \
    int wr = (wave >> 1) * 64, wc = (wave & 1) * 64;         \
    int row = lane & 15, quad = lane >> 4;

// QKV: h @ wqkv + b -> q (pre-scaled 1/16), k, vT[b,256,s]
__global__ __launch_bounds__(256) void gemm_qkv(
    const u16* __restrict__ h, const u16* __restrict__ wqkvT,
    const float* __restrict__ b_qkv,
    u16* __restrict__ q, u16* __restrict__ kk, u16* __restrict__ vT) {
    __shared__ u16 lds[GT2_ELEMS];
    f32x4 acc[4][4];
    ZERO_ACC4(acc)
    int m0 = blockIdx.x * 128, n0 = blockIdx.y * 128;
    gemm_tile2<256>(h, wqkvT, m0, n0, lds, acc);
    EPILOG_IDX4
    #pragma unroll
    for (int mi = 0; mi < 4; mi++) {
        #pragma unroll
        for (int nj = 0; nj < 4; nj++) {
            int gn = n0 + wc + nj * 16 + row;
            float bias = b_qkv[gn];
            int gm = m0 + wr + mi * 16 + quad * 4;
            if (gn < 256) {          // q, pre-scaled by 1/sqrt(D)=1/16
                #pragma unroll
                for (int r = 0; r < 4; r++)
                    q[(size_t)(gm + r) * 256 + gn] =
                        f2bf((acc[mi][nj][r] + bias) * 0.0625f);
            } else if (gn < 512) {   // k
                int col = gn - 256;
                #pragma unroll
                for (int r = 0; r < 4; r++)
                    kk[(size_t)(gm + r) * 256 + col] = f2bf(acc[mi][nj][r] + bias);
            } else {                 // v -> vT[b][d][s]
                int d = gn - 512;
                int b = gm >> 10, s = gm & 1023;
                ushort4 pack;
                pack.x = f2bf(acc[mi][nj][0] + bias);
                pack.y = f2bf(acc[mi][nj][1] + bias);
                pack.z = f2bf(acc[mi][nj][2] + bias);
                pack.w = f2bf(acc[mi][nj][3] + bias);
                *(ushort4*)(vT + ((size_t)(b * 256 + d) << 10) + s) = pack;
            }
        }
    }
}

// proj: ao @ wproj + b + residual(x fp32) -> x2 (bf16)
__global__ __launch_bounds__(256) void gemm_proj(
    const u16* __restrict__ ao, const u16* __restrict__ wprojT,
    const float* __restrict__ b_proj, const float* __restrict__ x_in,
    u16* __restrict__ x2) {
    __shared__ u16 lds[GT2_ELEMS];
    f32x4 acc[4][4];
    ZERO_ACC4(acc)
    int m0 = blockIdx.x * 128, n0 = blockIdx.y * 128;
    gemm_tile2<256>(ao, wprojT, m0, n0, lds, acc);
    EPILOG_IDX4
    #pragma unroll
    for (int mi = 0; mi < 4; mi++)
        #pragma unroll
        for (int nj = 0; nj < 4; nj++) {
            int gn = n0 + wc + nj * 16 + row;
            float bias = b_proj[gn];
            int gm = m0 + wr + mi * 16 + quad * 4;
            #pragma unroll
            for (int r = 0; r < 4; r++) {
                size_t idx = (size_t)(gm + r) * 256 + gn;
                x2[idx] = f2bf(acc[mi][nj][r] + bias + x_in[idx]);
            }
        }
}

// ---------------------------------------------------------------------------
// gemm_mlp: fused LN2 + fc1(ReLU) + fc2 + residual. One block per 128 rows,
// 256 threads, 128 KB LDS, 1 block/CU, grid 256.
//   R0 (64KB): x2 tile (LN'd in place) -> later reused for wfc2T
//   R1 (32KB): wfc1T k-half staging
//   R2 (32KB): a1 = relu(fc1) bf16 128x128
// All LDS tiles use the byte-XOR swizzle ((row&7)<<4) with pre-swizzled
// global sources (rule #21: same involution on write-side source and reads).
// Eliminates: ln2 kernel, h2 round-trip (33.5MB), a1 round-trip (16.8MB),
// and the unamortized K=128 standalone GEMM.
// ---------------------------------------------------------------------------
__global__ __launch_bounds__(256) void gemm_mlp(
    const u16* __restrict__ x2, const float* __restrict__ g2,
    const float* __restrict__ be2,
    const u16* __restrict__ wfc1T, const float* __restrict__ b_fc1,
    const u16* __restrict__ wfc2T, const float* __restrict__ b_fc2,
    float* __restrict__ out) {
    __shared__ u16 lds[65536];            // 128 KB
    u16* ldsB1 = lds + 32768;             // R1
    u16* ldsA1 = lds + 49152;             // R2
    const int tid = threadIdx.x;
    const int lane = tid & 63, wave = tid >> 6;
    const int rowl = lane & 15, quad = lane >> 4;
    const int wr = (wave >> 1) * 64, wc = (wave & 1) * 64;
    const int m0 = blockIdx.x * 128;

    // ---- stage x2 tile (128 x 512B) + wfc1T ks=0 half ----
    #pragma unroll
    for (int i = 0; i < 16; i++) {
        int blk = i * 4 + wave;
        int B = (blk << 10) + lane * 16;
        int r = B >> 9;
        int cb = (B & 511) ^ ((r & 7) << 4);
        gload16(x2 + (size_t)(m0 + r) * 256 + (cb >> 1), lds + (B >> 1));
    }
    #pragma unroll
    for (int i = 0; i < 8; i++) {
        int blk = i * 4 + wave;
        int B = (blk << 10) + lane * 16;
        int r = B >> 8;
        int cb = (B & 255) ^ ((r & 7) << 4);
        gload16(wfc1T + (size_t)r * 256 + 0 + (cb >> 1), ldsB1 + (B >> 1));
    }
    __syncthreads();

    // ---- LN2 in place: wave handles rows wave, wave+4, ... (32 rows) ----
    {
        float4 g4  = *(const float4*)(g2 + lane * 4);
        float4 be4 = *(const float4*)(be2 + lane * 4);
        #pragma unroll 4
        for (int i = 0; i < 32; i++) {
            int r = wave + i * 4;
            char* p = (char*)lds + r * 512 + ((lane * 8) ^ ((r & 7) << 4));
            ushort4 v = *(ushort4*)p;
            float f0 = bf2f(v.x), f1 = bf2f(v.y), f2v = bf2f(v.z), f3 = bf2f(v.w);
            float s  = f0 + f1 + f2v + f3;
            float sq = f0*f0 + f1*f1 + f2v*f2v + f3*f3;
            s = red16_sum(s);   s += __shfl_xor(s, 16);   s += __shfl_xor(s, 32);
            sq = red16_sum(sq); sq += __shfl_xor(sq, 16); sq += __shfl_xor(sq, 32);
            float mu   = s * (1.0f / 256.0f);
            float var  = sq * (1.0f / 256.0f) - mu * mu;
            float rstd = rsqrtf(var + EPSLN);
            ushort4 o;
            o.x = f2bf((f0  - mu) * rstd * g4.x + be4.x);
            o.y = f2bf((f1  - mu) * rstd * g4.y + be4.y);
            o.z = f2bf((f2v - mu) * rstd * g4.z + be4.z);
            o.w = f2bf((f3  - mu) * rstd * g4.w + be4.w);
            *(ushort4*)p = o;
        }
    }
    __syncthreads();

    // ---- fc1: h2tile(128x256) @ wfc1 -> acc1 (128x128) ----
    f32x4 acc1[4][4];
    ZERO_ACC4(acc1)
    #pragma unroll
    for (int ks = 0; ks < 256; ks += 128) {
        if (ks) {
            __syncthreads();          // done reading previous B1 half
            #pragma unroll
            for (int i = 0; i < 8; i++) {
                int blk = i * 4 + wave;
                int B = (blk << 10) + lane * 16;
                int r = B >> 8;
                int cb = (B & 255) ^ ((r & 7) << 4);
                gload16(wfc1T + (size_t)r * 256 + ks + (cb >> 1),
                        ldsB1 + (B >> 1));
            }
            __syncthreads();
        }
        #pragma unroll
        for (int k0 = 0; k0 < 128; k0 += 32) {
            bf16x8 a[4], b[4];
            #pragma unroll
            for (int mi = 0; mi < 4; mi++) {
                int rr = wr + mi * 16 + rowl;
                a[mi] = *(const bf16x8*)((const char*)lds + rr * 512 +
                         ((((ks + k0 + quad * 8) << 1)) ^ ((rr & 7) << 4)));
            }
            #pragma unroll
            for (int nj = 0; nj < 4; nj++) {
                int rb = wc + nj * 16 + rowl;
                b[nj] = *(const bf16x8*)((const char*)ldsB1 + rb * 256 +
                         ((((k0 + quad * 8) << 1)) ^ ((rb & 7) << 4)));
            }
            #pragma unroll
            for (int mi = 0; mi < 4; mi++)
                #pragma unroll
                for (int nj = 0; nj < 4; nj++)
                    acc1[mi][nj] = __builtin_amdgcn_mfma_f32_16x16x32_bf16(
                        a[mi], b[nj], acc1[mi][nj], 0, 0, 0);
        }
    }
    // relu+bias -> a1 (LDS, swizzled scalar writes)
    #pragma unroll
    for (int mi = 0; mi < 4; mi++)
        #pragma unroll
        for (int nj = 0; nj < 4; nj++) {
            int gn_l = wc + nj * 16 + rowl;
            float bias = b_fc1[gn_l];
            #pragma unroll
            for (int r = 0; r < 4; r++) {
                int gm_l = wr + mi * 16 + quad * 4 + r;
                *(u16*)((char*)ldsA1 + gm_l * 256 +
                        (((gn_l << 1)) ^ ((gm_l & 7) << 4))) =
                    f2bf(fmaxf(acc1[mi][nj][r] + bias, 0.0f));
            }
        }
    __syncthreads();                  // a1 visible; x2 tile (R0) now dead

    // ---- stage wfc2T (256 x 256B) into R0 ----
    #pragma unroll
    for (int i = 0; i < 16; i++) {
        int blk = i * 4 + wave;
        int B = (blk << 10) + lane * 16;
        int r = B >> 8;
        int cb = (B & 255) ^ ((r & 7) << 4);
        gload16(wfc2T + (size_t)r * 128 + (cb >> 1), lds + (B >> 1));
    }
    __syncthreads();

    // ---- fc2: a1(128x128) @ wfc2 -> out (128x256) + bias + residual ----
    const int wc2 = (wave & 1) * 128;
    f32x4 acc2[4][8];
    #pragma unroll
    for (int mi = 0; mi < 4; mi++)
        #pragma unroll
        for (int nj = 0; nj < 8; nj++)
            #pragma unroll
            for (int e = 0; e < 4; e++) acc2[mi][nj][e] = 0.0f;
    #pragma unroll
    for (int k0 = 0; k0 < 128; k0 += 32) {
        bf16x8 a[4], b[8];
        #pragma unroll
        for (int mi = 0; mi < 4; mi++) {
            int rr = wr + mi * 16 + rowl;
            a[mi] = *(const bf16x8*)((const char*)ldsA1 + rr * 256 +
                     ((((k0 + quad * 8) << 1)) ^ ((rr & 7) << 4)));
        }
        #pragma unroll
        for (int nj = 0; nj < 8; nj++) {
            int rb = wc2 + nj * 16 + rowl;
            b[nj] = *(const bf16x8*)((const char*)lds + rb * 256 +
                     ((((k0 + quad * 8) << 1)) ^ ((rb & 7) << 4)));
        }
        #pragma unroll
        for (int mi = 0; mi < 4; mi++)
            #pragma unroll
            for (int nj = 0; nj < 8; nj++)
                acc2[mi][nj] = __builtin_amdgcn_mfma_f32_16x16x32_bf16(
                    a[mi], b[nj], acc2[mi][nj], 0, 0, 0);
    }
    #pragma unroll
    for (int mi = 0; mi < 4; mi++)
        #pragma unroll
        for (int nj = 0; nj < 8; nj++) {
            int gn = wc2 + nj * 16 + rowl;
            float bias = b_fc2[gn];
            int gm = m0 + wr + mi * 16 + quad * 4;
            #pragma unroll
            for (int r = 0; r < 4; r++) {
                size_t idx = (size_t)(gm + r) * 256 + gn;
                out[idx] = acc2[mi][nj][r] + bias + bf2f(x2[idx]);
            }
        }
}

// ---------------------------------------------------------------------------
// Flash attention v8: v5 structure (64 q-rows/block, 4 waves x 16 rows,
// measured 62 us) with V SINGLE-BUFFERED -> LDS 53 KB -> 3 blocks/CU
// (12 waves, +50% TLP; was the occupancy cap at 69 KB / 2 blocks).
// Iteration: prefetch K[t+1] (dbuf) -> compute QK/softmax/PV -> barrier
// (everyone done with V[t]) -> stage V[t+1] into the single buffer ->
// barrier (drain). V-drain exposure is covered by the 3rd resident block.
// Work table re-balanced for co-resident TRIPLES {w, w+8, w+16}: max 36.
// ---------------------------------------------------------------------------
__constant__ unsigned char WQT[24] = {7,15,15,14,14,6,13,13,
                                      4,10,10,5,11,11,12,12,
                                      9,0,1,2,3,9,8,8};
__constant__ unsigned char WH[24]  = {2,0,1,0,1,2,0,1,
                                      2,0,1,2,0,1,0,1,
                                      0,2,2,2,2,1,0,1};

__global__ __launch_bounds__(256) void attn_kernel(
    const u16* __restrict__ q, const u16* __restrict__ k,
    const u16* __restrict__ vT, u16* __restrict__ ao,
    u16* __restrict__ part, float* __restrict__ ml) {
    __shared__ u16 k_lds[2][32 * 256];   // 2 x 16 KB, K tile [s][d]
    __shared__ u16 v_lds[256 * 32];      // 16 KB, V^T tile [d][s] (single buf)
    __shared__ u16 p_lds[4][16 * 40];    // 5 KB, wave-private P staging

    int j = blockIdx.x;
    int b = j & 31, w = j >> 5;          // batch fast-varying: XCD = b % 8
    int qt = WQT[w], hh = WH[w];
    int lo, hi;
    if (hh == 2) { lo = 0; hi = 2 * qt + 2; }
    else         { lo = hh * (qt + 1); hi = lo + qt + 1; }

    int tid = threadIdx.x;
    int lane = tid & 63, wave = tid >> 6;
    int row = lane & 15, quad = lane >> 4;
    int q0 = qt * 64;
    int qrow0 = q0 + wave * 16;

    const u16* qb = q + ((size_t)b << 10) * 256;
    const u16* kb = k + ((size_t)b << 10) * 256;
    const u16* vb = vT + (((size_t)b * 256) << 10);

    const int kxor = (row & 7) << 3;   // u16-unit XOR for K reads
    const int vxor = (row & 6) << 2;   // u16-unit XOR for V reads

    // Q fragments held in registers for the whole kernel (pre-scaled by 1/16)
    bf16x8 qf[8];
    #pragma unroll
    for (int kf = 0; kf < 8; kf++)
        qf[kf] = *(const bf16x8*)(qb + (size_t)(qrow0 + row) * 256 + kf * 32 + quad * 8);

    f32x4 o[16];
    #pragma unroll
    for (int n = 0; n < 16; n++)
        #pragma unroll
        for (int e = 0; e < 4; e++) o[n][e] = 0.0f;
    float m_i[4], l_i[4];
    #pragma unroll
    for (int r = 0; r < 4; r++) { m_i[r] = -1e30f; l_i[r] = 0.0f; }

    int wlast = 2 * qt + (wave >> 1);    // last k-tile this wave computes

    auto stageK = [&](int bf, int kt) {
        int k0 = kt << 5;
        #pragma unroll
        for (int c = 0; c < 4; c++) {
            int blk = wave * 4 + c;
            int B = (blk << 10) + lane * 16;
            int rk = B >> 9;
            int ck = (B & 511) ^ ((rk & 7) << 4);
            gload16(kb + (size_t)(k0 + rk) * 256 + (ck >> 1),
                    &k_lds[bf][blk << 9]);
        }
    };
    auto stageV = [&](int kt) {
        int k0 = kt << 5;
        #pragma unroll
        for (int c = 0; c < 4; c++) {
            int blk = wave * 4 + c;
            int B = (blk << 10) + lane * 16;
            int rv = B >> 6;
            int cv = (B & 63) ^ ((rv & 6) << 3);
            gload16(vb + ((size_t)rv << 10) + k0 + (cv >> 1),
                    &v_lds[blk << 9]);
        }
    };

    stageK(0, lo);
    stageV(lo);
    __syncthreads();                       // vmcnt(0) drain + barrier

    for (int kt = lo; kt < hi; kt++) {
        int cur = (kt - lo) & 1;
        if (kt + 1 < hi) stageK(cur ^ 1, kt + 1);   // K prefetch (dbuf)
        if (kt <= wlast) {
            const u16* kl = k_lds[cur];
            const u16* vl = v_lds;

            // S = Q K^T : 16 x 32
            f32x4 sf[2];
            #pragma unroll
            for (int jn = 0; jn < 2; jn++)
                #pragma unroll
                for (int e = 0; e < 4; e++) sf[jn][e] = 0.0f;
            __builtin_amdgcn_s_setprio(1);
            #pragma unroll
            for (int kf = 0; kf < 8; kf++)
                #pragma unroll
                for (int jn = 0; jn < 2; jn++) {
                    bf16x8 bfrag = *(const bf16x8*)(kl +
                        ((((jn * 16 + row) * 256) + kf * 32 + quad * 8) ^ kxor));
                    sf[jn] = __builtin_amdgcn_mfma_f32_16x16x32_bf16(
                        qf[kf], bfrag, sf[jn], 0, 0, 0);
                }
            __builtin_amdgcn_s_setprio(0);

            int kk0 = kt * 32;
            bool diag = (kt == wlast);     // only the diagonal tile masks
            int qrow = qrow0 + quad * 4;
            float sv[2][4];
            #pragma unroll
            for (int jn = 0; jn < 2; jn++)
                #pragma unroll
                for (int r = 0; r < 4; r++) {
                    float v = sf[jn][r];
                    if (diag && (kk0 + jn * 16 + row > qrow + r)) v = MASKV;
                    sv[jn][r] = v;
                }

            // online softmax with defer-max (THR=8); DPP reduces (VALU pipe)
            float pmax[4];
            int need = 0;
            #pragma unroll
            for (int r = 0; r < 4; r++) {
                pmax[r] = red16_max(fmaxf(sv[0][r], sv[1][r]));
                need |= (pmax[r] > m_i[r] + 8.0f) ? 1 : 0;
            }
            if (__any(need)) {
                #pragma unroll
                for (int r = 0; r < 4; r++) {
                    float mnew = fmaxf(m_i[r], pmax[r]);
                    float al = __expf(m_i[r] - mnew);
                    m_i[r] = mnew;
                    l_i[r] *= al;
                    #pragma unroll
                    for (int n = 0; n < 16; n++) o[n][r] *= al;
                }
            }
            #pragma unroll
            for (int r = 0; r < 4; r++) {
                float ps = 0.0f;
                #pragma unroll
                for (int jn = 0; jn < 2; jn++) {
                    sv[jn][r] = __expf(sv[jn][r] - m_i[r]);
                    ps += sv[jn][r];
                }
                l_i[r] += red16_sum(ps);
            }

            // P: C-layout -> wave-private LDS -> A-layout (one frag, K=32)
            u16* pw = p_lds[wave];
            #pragma unroll
            for (int jn = 0; jn < 2; jn++)
                #pragma unroll
                for (int r = 0; r < 4; r++)
                    pw[(quad * 4 + r) * 40 + jn * 16 + row] = f2bf(sv[jn][r]);
            bf16x8 pf = *(const bf16x8*)(pw + row * 40 + quad * 8);

            // O += P V
            __builtin_amdgcn_s_setprio(1);
            #pragma unroll
            for (int n = 0; n < 16; n++) {
                bf16x8 bv = *(const bf16x8*)(vl +
                    ((((n * 16 + row) * 32) + quad * 8) ^ vxor));
                o[n] = __builtin_amdgcn_mfma_f32_16x16x32_bf16(pf, bv, o[n], 0, 0, 0);
            }
            __builtin_amdgcn_s_setprio(0);
        }
        __syncthreads();                   // all waves done reading V[t]
        if (kt + 1 < hi) stageV(kt + 1);   // overwrite the single V buffer
        __syncthreads();                   // V[t+1] landed (vmcnt drain)
    }

    if (hh == 2) {
        // full block: normalize and store final bf16
        float inv[4];
        #pragma unroll
        for (int r = 0; r < 4; r++) inv[r] = 1.0f / l_i[r];
        u16* aob = ao + (((size_t)b << 10) + qrow0) * 256;
        #pragma unroll
        for (int r = 0; r < 4; r++)
            #pragma unroll
            for (int n = 0; n < 16; n++)
                aob[(size_t)(quad * 4 + r) * 256 + n * 16 + row] =
                    f2bf(o[n][r] * inv[r]);
    } else {
        // split half: write unnormalized O (bf16) + per-row (m,l)
        int p = (((b << 3) | (qt - 8)) << 1) | hh;
        u16* pb = part + (((size_t)p) << 6) * 256;
        #pragma unroll
        for (int r = 0; r < 4; r++) {
            int rt = wave * 16 + quad * 4 + r;
            #pragma unroll
            for (int n = 0; n < 16; n++)
                pb[(size_t)rt * 256 + n * 16 + row] = f2bf(o[n][r]);
        }
        if (row == 0) {
            #pragma unroll
            for (int r = 0; r < 4; r++) {
                int rt = wave * 16 + quad * 4 + r;
                float2 v2; v2.x = m_i[r]; v2.y = l_i[r];
                *(float2*)(ml + ((size_t)((p << 6) + rt)) * 2) = v2;
            }
        }
    }
}

// Merge the two k-range halves for qt 8..15: standard (m,l,O) combine.
__global__ __launch_bounds__(256) void attn_merge(
    const u16* __restrict__ part, const float* __restrict__ ml,
    u16* __restrict__ ao) {
    int j = blockIdx.x;                  // 0..255 : b*8 + (qt-8)
    int b = j >> 3, qi = j & 7;
    int t = threadIdx.x;
    int r = t >> 2, cq = t & 3;          // row 0..63, col-quarter 0..3
    int pA = j << 1, pB = pA | 1;
    const float* mlA = ml + ((size_t)(pA << 6) + r) * 2;
    const float* mlB = ml + ((size_t)(pB << 6) + r) * 2;
    float mA = mlA[0], lA = mlA[1];
    float mB = mlB[0], lB = mlB[1];
    float m  = fmaxf(mA, mB);
    float eA = __expf(mA - m), eB = __expf(mB - m);
    float inv = 1.0f / (lA * eA + lB * eB);
    float sA = eA * inv, sB = eB * inv;
    const u16* oA = part + (((size_t)(pA << 6) + r) * 256) + cq * 64;
    const u16* oB = part + (((size_t)(pB << 6) + r) * 256) + cq * 64;
    u16* dst = ao + ((size_t)((b << 10) + 512 + (qi << 6) + r)) * 256 + cq * 64;
    #pragma unroll
    for (int u = 0; u < 8; u++) {
        U8 a, bb, o;
        a.v  = *(const uint4*)(oA + u * 8);
        bb.v = *(const uint4*)(oB + u * 8);
        #pragma unroll
        for (int e = 0; e < 8; e++)
            o.s[e] = f2bf(bf2f(a.s[e]) * sA + bf2f(bb.s[e]) * sB);
        *(uint4*)(dst + u * 8) = o.v;
    }
}

// ---------------------------------------------------------------------------
extern "C" void kernel_launch(void* const* d_in, const int* in_sizes, int n_in,
                              void* d_out, int out_size, void* d_ws, size_t ws_size,
                              hipStream_t stream) {
    const float* x      = (const float*)d_in[0];
    const float* ln1_s  = (const float*)d_in[1];
    const float* ln1_b  = (const float*)d_in[2];
    const float* w_qkv  = (const float*)d_in[3];
    const float* b_qkv  = (const float*)d_in[4];
    const float* w_proj = (const float*)d_in[5];
    const float* b_proj = (const float*)d_in[6];
    const float* ln2_s  = (const float*)d_in[7];
    const float* ln2_b  = (const float*)d_in[8];
    const float* w_fc1  = (const float*)d_in[9];
    const float* b_fc1  = (const float*)d_in[10];
    const float* w_fc2  = (const float*)d_in[11];
    const float* b_fc2  = (const float*)d_in[12];
    float* out = (float*)d_out;

    // d_out reuse: h (LN1 out) dies after gemm_qkv -> region reused for attn
    // split partials; (m,l) at the 16.8MB offset, consumed by attn_merge
    // before gemm_mlp overwrites all of d_out with the final fp32 output.
    u16* h  = (u16*)d_out;                     // LN1(x), then attn partial O
    u16* h2 = h + (size_t)NROWS * 256;         // attn (m,l) scratch

    u16* W = (u16*)d_ws;
    u16* wqkvT  = W;                           // 768*256
    u16* wprojT = wqkvT + 196608;              // 256*256
    u16* wfc1T  = wprojT + 65536;              // 128*256
    u16* wfc2T  = wfc1T + 32768;               // 256*128
    u16* buf1   = wfc2T + 32768;               // q, then attn-out (in place)
    u16* buf2   = buf1 + (size_t)NROWS * 256;  // k, then x2
    u16* buf3   = buf2 + (size_t)NROWS * 256;  // vT (dead after attn)

    u16*   part  = h;                          // attn partial O (bf16)
    float* mlbuf = (float*)h2;                 // attn partial (m,l)

    transpose_weights<<<dim3(64), dim3(256), 0, stream>>>(
        w_qkv, wqkvT, w_proj, wprojT, w_fc1, wfc1T, w_fc2, wfc2T);
    ln_fused<float><<<dim3(NROWS / 4), dim3(256), 0, stream>>>(
        x, ln1_s, ln1_b, h);
    gemm_qkv<<<dim3(NROWS / 128, 6), dim3(256), 0, stream>>>(
        h, wqkvT, b_qkv, buf1, buf2, buf3);
    attn_kernel<<<dim3(768), dim3(256), 0, stream>>>(
        buf1, buf2, buf3, buf1, part, mlbuf);
    attn_merge<<<dim3(256), dim3(256), 0, stream>>>(
        part, mlbuf, buf1);
    gemm_proj<<<dim3(NROWS / 128, 2), dim3(256), 0, stream>>>(
        buf1, wprojT, b_proj, x, buf2);
    gemm_mlp<<<dim3(NROWS / 128), dim3(256), 0, stream>>>(
        buf2, ln2_s, ln2_b, wfc1T, b_fc1, wfc2T, b_fc2, out);
}